// Round 10
// baseline (352.922 us; speedup 1.0000x reference)
//
#include <hip/hip_runtime.h>
#include <float.h>
#include <math.h>

// ---------------- problem constants ----------------
#define B_   2
#define N_   2048
#define D_   512
#define H_   8
#define DH_  64
#define NM_  2047            // n-1
#define SCALE_F 0.125f       // 64^-0.5
#define LBK 72               // LDS row pad (bf16 tiles), 144B: 16B-aligned rows

typedef __attribute__((ext_vector_type(8))) short bf16x8;
typedef __attribute__((ext_vector_type(4))) float f32x4;
#define MFMA_B16(a,b,c) __builtin_amdgcn_mfma_f32_16x16x32_bf16(a,b,c,0,0,0)

__device__ __forceinline__ short f2bf(float f){
  unsigned u = __float_as_uint(f);
  unsigned r = u + 0x7fffu + ((u>>16)&1u);
  return (short)(r>>16);
}
__device__ __forceinline__ float bf2f(short s){
  return __uint_as_float(((unsigned)(unsigned short)s)<<16);
}
__device__ __forceinline__ void lds_fence(){
  asm volatile("s_waitcnt lgkmcnt(0)" ::: "memory");
  __builtin_amdgcn_sched_barrier(0);
}
// load a 64x64 bf16 tile into regs (2 int4 per thread); pairs with twrite
__device__ __forceinline__ void tload(const short* __restrict__ src, size_t stride,
                                      int tid, int4& r0, int4& r1){
  int rr = tid>>2, cc = (tid&3)<<4;
  r0 = *(const int4*)&src[(size_t)rr*stride + cc];
  r1 = *(const int4*)&src[(size_t)rr*stride + cc + 8];
}
__device__ __forceinline__ void twrite(short (*dst)[LBK], int tid,
                                       const int4& r0, const int4& r1){
  int rr = tid>>2, cc = (tid&3)<<4;
  *(int4*)&dst[rr][cc]   = r0;
  *(int4*)&dst[rr][cc+8] = r1;
}
__device__ __forceinline__ float wred64(float v){
  #pragma unroll
  for(int off=32; off; off>>=1) v += __shfl_down(v, off, 64);
  return v;
}

// 64x64 MFMA GEMM mainloop with register-prefetch double buffering (2-phase)
__device__ __forceinline__ void gemm64(const short* __restrict__ A, size_t lda,
    const short* __restrict__ Bt, size_t ldb, int nk,
    short (*as)[LBK], short (*bs)[LBK], f32x4* acc){
  int tid=threadIdx.x, w=tid>>6, lane=tid&63, lg=lane>>4, ln=lane&15;
  int4 a0,a1,b0,b1;
  tload(A, lda, tid, a0,a1);
  tload(Bt, ldb, tid, b0,b1);
  for(int kt=0;kt<nk;++kt){
    __syncthreads();
    twrite(as, tid, a0,a1);
    twrite(bs, tid, b0,b1);
    if(kt+1<nk){
      tload(A +(size_t)(kt+1)*64, lda, tid, a0,a1);
      tload(Bt+(size_t)(kt+1)*64, ldb, tid, b0,b1);
    }
    __syncthreads();
    __builtin_amdgcn_s_setprio(1);
    #pragma unroll
    for(int s=0;s<2;s++){
      bf16x8 a = *(const bf16x8*)&as[w*16+ln][32*s+lg*8];
      #pragma unroll
      for(int nb=0;nb<4;nb++){
        bf16x8 b = *(const bf16x8*)&bs[nb*16+ln][32*s+lg*8];
        acc[nb]=MFMA_B16(a,b,acc[nb]);
      }
    }
    __builtin_amdgcn_s_setprio(0);
  }
}

// ---------------- 1. RMSNorm -> tb (bf16, padded to 4160 rows) ----------------
__global__ __launch_bounds__(256) void k_rmsnorm(const float* __restrict__ tok,
    const float* __restrict__ w, short* __restrict__ tb){
  int row = blockIdx.x;
  int tid = threadIdx.x;
  if(row>=4096){ tb[(size_t)row*D_+tid]=0; tb[(size_t)row*D_+tid+256]=0; return; }
  const float* x = tok + (size_t)row*D_;
  float v0 = x[tid], v1 = x[tid+256];
  float s = v0*v0 + v1*v1;
  s = wred64(s);
  __shared__ float red[4];
  if((tid&63)==0) red[tid>>6] = s;
  __syncthreads();
  float tot = red[0]+red[1]+red[2]+red[3];
  float sc = rsqrtf(tot*(1.f/512.f) + 1.1920929e-7f);
  tb[(size_t)row*D_+tid]     = f2bf(v0*sc*w[tid]);
  tb[(size_t)row*D_+tid+256] = f2bf(v1*sc*w[tid+256]);
}

// ---------------- 2. weight prep ----------------
__global__ __launch_bounds__(256) void k_wprep(const float* __restrict__ wq,
    const float* __restrict__ wk, const float* __restrict__ wv,
    const float* __restrict__ wo, const float* __restrict__ tvw,
    short* __restrict__ wqt, short* __restrict__ wkt, short* __restrict__ wvt,
    short* __restrict__ wob, short* __restrict__ wot, short* __restrict__ tvwb){
  __shared__ short l[64][66];
  int bx=blockIdx.x, tid=threadIdx.x;
  if(bx<192){
    const float* w = (bx<64)? wq : (bx<128)? wk : wv;
    short* wt      = (bx<64)? wqt: (bx<128)? wkt: wvt;
    int lb=bx&63, h=lb>>3, d0=(lb&7)*64;
    for(int kk=0;kk<16;kk++){
      int idx=kk*256+tid, rr=idx>>6, cc=idx&63;
      l[cc][rr] = f2bf(w[((size_t)h*512 + d0+rr)*64 + cc]);
    }
    __syncthreads();
    for(int kk=0;kk<16;kk++){
      int idx=kk*256+tid, rr=idx>>6, cc=idx&63;
      wt[((size_t)h*64+rr)*512 + d0+cc] = l[rr][cc];
    }
  } else if(bx<256){
    int lb=bx-192, r0=(lb>>3)*64, c0=(lb&7)*64;
    for(int kk=0;kk<16;kk++){
      int idx=kk*256+tid, rr=idx>>6, cc=idx&63;
      l[cc][rr] = f2bf(wo[(size_t)(r0+rr)*512 + c0+cc]);
    }
    __syncthreads();
    for(int kk=0;kk<16;kk++){
      int idx=kk*256+tid, rr=idx>>6, cc=idx&63;
      wot[(size_t)(c0+rr)*512 + r0+cc] = l[rr][cc];
    }
  } else if(bx<264){
    size_t base=(size_t)(bx-256)*32768;
    for(int kk=0;kk<128;kk++) wob[base+kk*256+tid]=f2bf(wo[base+kk*256+tid]);
  } else {
    size_t base=(size_t)(bx-264)*32768;
    for(int kk=0;kk<128;kk++) tvwb[base+kk*256+tid]=f2bf(tvw[base+kk*256+tid]);
  }
}

// ---------------- 3. transposes (4096x512) ----------------
__global__ __launch_bounds__(256) void k_trans_b(const short* __restrict__ in,
    short* __restrict__ outt){
  __shared__ short l[64][66];
  int r0=blockIdx.x<<6, c0=blockIdx.y<<6, tid=threadIdx.x;
  for(int kk=0;kk<16;kk++){
    int idx=kk*256+tid, rr=idx>>6, cc=idx&63;
    l[cc][rr]=in[(size_t)(r0+rr)*512 + c0+cc];
  }
  __syncthreads();
  for(int kk=0;kk<16;kk++){
    int idx=kk*256+tid, rr=idx>>6, cc=idx&63;
    outt[(size_t)(c0+rr)*4096 + r0+cc]=l[rr][cc];
  }
}
__global__ __launch_bounds__(256) void k_trans_f(const float* __restrict__ in,
    short* __restrict__ outn, short* __restrict__ outt){
  __shared__ short l[64][66];
  int r0=blockIdx.x<<6, c0=blockIdx.y<<6, tid=threadIdx.x;
  for(int kk=0;kk<16;kk++){
    int idx=kk*256+tid, rr=idx>>6, cc=idx&63;
    short v=f2bf(in[(size_t)(r0+rr)*512 + c0+cc]);
    outn[(size_t)(r0+rr)*512 + c0+cc]=v;
    l[cc][rr]=v;
  }
  __syncthreads();
  for(int kk=0;kk<16;kk++){
    int idx=kk*256+tid, rr=idx>>6, cc=idx&63;
    outt[(size_t)(c0+rr)*4096 + r0+cc]=l[rr][cc];
  }
}

// ---------------- 4. QKV projection (MFMA) ----------------
__global__ __launch_bounds__(256) void k_gemm_qkv(const short* __restrict__ tb,
    const short* __restrict__ wqt, const short* __restrict__ wkt, const short* __restrict__ wvt,
    short* __restrict__ qh, short* __restrict__ kh, short* __restrict__ vh,
    short* __restrict__ qt, short* __restrict__ kt, short* __restrict__ vt){
  __shared__ __attribute__((aligned(16))) short as[64][LBK], bs[64][LBK];
  int r0=blockIdx.x<<6, ct=blockIdx.y, which=ct>>3, h=ct&7;
  const short* Bt=(which==0?wqt:which==1?wkt:wvt)+(size_t)h*32768;
  f32x4 acc[4];
  #pragma unroll
  for(int nb=0;nb<4;nb++) acc[nb]=(f32x4){0.f,0.f,0.f,0.f};
  gemm64(tb+(size_t)r0*512, 512, Bt, 512, 8, as, bs, acc);
  short* on=(which==0?qh:which==1?kh:vh);
  short* ot=(which==0?qt:which==1?kt:vt);
  int tid=threadIdx.x, w=tid>>6, lane=tid&63, lg=lane>>4, ln=lane&15;
  size_t bh=(size_t)(r0>>11)*8+h;
  int n0=(r0&2047)+w*16+lg*4;
  #pragma unroll
  for(int nb=0;nb<4;nb++){
    int e=nb*16+ln;
    short4 s4;
    s4.x=f2bf(acc[nb][0]); s4.y=f2bf(acc[nb][1]);
    s4.z=f2bf(acc[nb][2]); s4.w=f2bf(acc[nb][3]);
    on[(bh*2048+n0  )*64+e]=s4.x;
    on[(bh*2048+n0+1)*64+e]=s4.y;
    on[(bh*2048+n0+2)*64+e]=s4.z;
    on[(bh*2048+n0+3)*64+e]=s4.w;
    *(short4*)&ot[(bh*64+e)*2048+n0]=s4;
  }
}

// ---------------- 5. flash fwd: paired i-tiles (2a,2a+1) + 2-way j-split ----------------
// grid (16 bh, 32 y): y<16 -> a=y, half=0 ; y>=16 -> a=31-y, half=1.
__global__ __launch_bounds__(256) void k_fa_fwd(const short* __restrict__ qh,
    const short* __restrict__ kh, const short* __restrict__ vt,
    float* __restrict__ op0, float* __restrict__ op1, float* __restrict__ mlb){
  int bh = blockIdx.x, y = blockIdx.y;
  int a    = (y<16)? y : 31-y;
  int half = (y<16)? 0 : 1;
  int itA = 2*a, itB = 2*a+1;
  const short* qhb = qh + (size_t)bh*N_*DH_;
  const short* khb = kh + (size_t)bh*N_*DH_;
  const short* vtb = vt + (size_t)bh*DH_*N_;
  __shared__ __attribute__((aligned(16))) short ks[64][LBK], vts[64][LBK];
  __shared__ __attribute__((aligned(16))) short psb[2][4][16][LBK];
  int tid=threadIdx.x, w=tid>>6, lane=tid&63, lg=lane>>4, ln=lane&15;
  bf16x8 aq[2][2];
  #pragma unroll
  for(int sd=0;sd<2;sd++){
    int i0=(sd?itB:itA)<<6;
    #pragma unroll
    for(int s=0;s<2;s++)
      aq[sd][s] = *(const bf16x8*)&qhb[(size_t)(i0+w*16+ln)*DH_ + 32*s + lg*8];
  }
  f32x4 acc[2][4];
  float mrow[2][4], lrow[2][4];
  #pragma unroll
  for(int sd=0;sd<2;sd++){
    #pragma unroll
    for(int nb=0;nb<4;nb++) acc[sd][nb]=(f32x4){0.f,0.f,0.f,0.f};
    #pragma unroll
    for(int r=0;r<4;r++){ mrow[sd][r]=-FLT_MAX; lrow[sd][r]=0.f; }
  }
  int4 ka0,ka1,va0,va1;
  tload(khb+(size_t)half*64*DH_, DH_, tid, ka0,ka1);
  tload(vtb+half*64, N_, tid, va0,va1);
  for(int jt=half;jt<=itB;jt+=2){
    int j0 = jt<<6;
    bool actA = (jt<=itA);
    __syncthreads();
    twrite(ks, tid, ka0,ka1);
    twrite(vts, tid, va0,va1);
    if(jt+2<=itB){
      tload(khb+(size_t)(jt+2)*64*DH_, DH_, tid, ka0,ka1);
      tload(vtb+(jt+2)*64, N_, tid, va0,va1);
    }
    __syncthreads();
    f32x4 sv[2][4];
    __builtin_amdgcn_s_setprio(1);
    #pragma unroll
    for(int nb=0;nb<4;nb++){
      f32x4 z0={0.f,0.f,0.f,0.f}, z1={0.f,0.f,0.f,0.f};
      #pragma unroll
      for(int s=0;s<2;s++){
        bf16x8 bk = *(const bf16x8*)&ks[nb*16+ln][32*s + lg*8];
        z0 = MFMA_B16(aq[0][s], bk, z0);
        z1 = MFMA_B16(aq[1][s], bk, z1);
      }
      sv[0][nb]=z0; sv[1][nb]=z1;
    }
    __builtin_amdgcn_s_setprio(0);
    #pragma unroll
    for(int sd=0;sd<2;sd++){
      if(sd==0 && !actA) continue;
      int it_ = sd? itB : itA;
      int i0  = it_<<6;
      bool diag = (jt==it_);
      int iiB = i0 + w*16 + lg*4;
      #pragma unroll
      for(int r=0;r<4;r++){
        int ii = iiB + r;
        float srow[4]; float mx = -FLT_MAX;
        if(diag){
          #pragma unroll
          for(int nb=0;nb<4;nb++){
            float x = sv[sd][nb][r]*SCALE_F;
            if(j0+nb*16+ln > ii) x = -FLT_MAX;
            srow[nb]=x; mx=fmaxf(mx,x);
          }
        } else {
          #pragma unroll
          for(int nb=0;nb<4;nb++){
            float x = sv[sd][nb][r]*SCALE_F;
            srow[nb]=x; mx=fmaxf(mx,x);
          }
        }
        mx=fmaxf(mx,__shfl_xor(mx,1)); mx=fmaxf(mx,__shfl_xor(mx,2));
        mx=fmaxf(mx,__shfl_xor(mx,4)); mx=fmaxf(mx,__shfl_xor(mx,8));
        float mn = fmaxf(mrow[sd][r], mx);
        float rs = 0.f;
        #pragma unroll
        for(int nb=0;nb<4;nb++){
          float pv = __expf(srow[nb]-mn);
          psb[sd][w][lg*4+r][ln+16*nb]=f2bf(pv); rs+=pv;
        }
        rs+=__shfl_xor(rs,1); rs+=__shfl_xor(rs,2);
        rs+=__shfl_xor(rs,4); rs+=__shfl_xor(rs,8);
        float corr = __expf(mrow[sd][r]-mn);
        lrow[sd][r]=lrow[sd][r]*corr+rs; mrow[sd][r]=mn;
        #pragma unroll
        for(int nb=0;nb<4;nb++) acc[sd][nb][r]*=corr;
      }
    }
    lds_fence();
    __builtin_amdgcn_s_setprio(1);
    #pragma unroll
    for(int nb=0;nb<4;nb++){
      #pragma unroll
      for(int s=0;s<2;s++){
        bf16x8 bv = *(const bf16x8*)&vts[nb*16+ln][32*s + lg*8];
        bf16x8 pa1 = *(const bf16x8*)&psb[1][w][ln][32*s + lg*8];
        acc[1][nb] = MFMA_B16(pa1, bv, acc[1][nb]);
        if(actA){
          bf16x8 pa0 = *(const bf16x8*)&psb[0][w][ln][32*s + lg*8];
          acc[0][nb] = MFMA_B16(pa0, bv, acc[0][nb]);
        }
      }
    }
    __builtin_amdgcn_s_setprio(0);
    lds_fence();
  }
  float* op   = half? op1 : op0;
  float* marr = mlb + half*65536;
  float* larr = marr + 32768;
  #pragma unroll
  for(int sd=0;sd<2;sd++){
    int i0=(sd?itB:itA)<<6;
    #pragma unroll
    for(int r=0;r<4;r++){
      int ii = i0 + w*16 + lg*4 + r;
      size_t row = (size_t)bh*2048 + ii;
      #pragma unroll
      for(int nb=0;nb<4;nb++)
        op[row*64 + nb*16+ln] = acc[sd][nb][r];
      if(ln==0){ marr[row]=mrow[sd][r]; larr[row]=lrow[sd][r]; }
    }
  }
}

// merge two softmax partials -> obb bf16 + lse
__global__ __launch_bounds__(256) void k_fa_merge(const float* __restrict__ op0,
    const float* __restrict__ op1, const float* __restrict__ mlb,
    short* __restrict__ obb, float* __restrict__ lse){
  int row = blockIdx.x*4 + (threadIdx.x>>6);
  int lane = threadIdx.x&63;
  float m0 = mlb[row],        l0 = mlb[32768+row];
  float m1 = mlb[65536+row],  l1 = mlb[98304+row];
  float m  = fmaxf(m0,m1);
  float c0 = __expf(m0-m), c1 = __expf(m1-m);
  float l  = l0*c0 + l1*c1;
  float o  = (op0[(size_t)row*64+lane]*c0 + op1[(size_t)row*64+lane]*c1)/l;
  int bh = row>>11, i = row&2047, b = bh>>3, h = bh&7;
  obb[((size_t)(b*2048+i))*512 + h*64 + lane] = f2bf(o);
  if(lane==0) lse[row] = m + logf(l);
}

// ---------------- 6. pred = obb @ wot^T (MFMA), f32 out ----------------
__global__ __launch_bounds__(256) void k_gemm_pred(const short* __restrict__ obb,
    const short* __restrict__ wot, float* __restrict__ pred){
  __shared__ __attribute__((aligned(16))) short as[64][LBK], bs[64][LBK];
  int r0=blockIdx.x<<6, c0=blockIdx.y<<6;
  f32x4 acc[4];
  #pragma unroll
  for(int nb=0;nb<4;nb++) acc[nb]=(f32x4){0.f,0.f,0.f,0.f};
  gemm64(obb+(size_t)r0*512, 512, wot+(size_t)c0*512, 512, 8, as, bs, acc);
  int tid=threadIdx.x, w=tid>>6, lane=tid&63, lg=lane>>4, ln=lane&15;
  int row=r0+w*16+lg*4;
  #pragma unroll
  for(int nb=0;nb<4;nb++)
    #pragma unroll
    for(int r=0;r<4;r++)
      pred[(size_t)(row+r)*512 + c0+nb*16+ln]=acc[nb][r];
}

// ---------------- 7. tv = tb(shift+1) @ tvwb^T ----------------
__global__ __launch_bounds__(256) void k_gemm_tv(const short* __restrict__ tb,
    const short* __restrict__ tvwb, float* __restrict__ er){
  __shared__ __attribute__((aligned(16))) short as[64][LBK], bs[64][LBK];
  int r0=blockIdx.x<<6, c0=blockIdx.y<<6;
  f32x4 acc[4];
  #pragma unroll
  for(int nb=0;nb<4;nb++) acc[nb]=(f32x4){0.f,0.f,0.f,0.f};
  gemm64(tb+(size_t)(r0+1)*512, 512, tvwb+(size_t)c0*512, 512, 8, as, bs, acc);
  int tid=threadIdx.x, w=tid>>6, lane=tid&63, lg=lane>>4, ln=lane&15;
  int row=r0+w*16+lg*4;
  #pragma unroll
  for(int nb=0;nb<4;nb++)
    #pragma unroll
    for(int r=0;r<4;r++){
      float v=(((row+r)&2047)==2047)?0.f:acc[nb][r];
      er[(size_t)(row+r)*512 + c0+nb*16+ln]=v;
    }
}

// ---------------- 8. layernorm target + lr + error ----------------
__global__ __launch_bounds__(256) void k_lnerr(float* __restrict__ er,
    const short* __restrict__ tb, const float* __restrict__ pred,
    const float* __restrict__ lrw){
  int kr = blockIdx.x;
  int b = kr/NM_, n = kr-b*NM_;
  size_t row=(size_t)b*2048+n;
  float* tv = er + row*512;
  const short* tok = tb + row*512;
  const float* pr  = pred + row*512;
  int tid=threadIdx.x;
  float v0=tv[tid], v1=tv[tid+256];
  float s1=v0+v1, s2=v0*v0+v1*v1;
  float s3=bf2f(tok[tid])*lrw[tid] + bf2f(tok[tid+256])*lrw[tid+256];
  s1=wred64(s1); s2=wred64(s2); s3=wred64(s3);
  __shared__ float r1[4],r2[4],r3[4];
  if((tid&63)==0){ int w=tid>>6; r1[w]=s1; r2[w]=s2; r3[w]=s3; }
  __syncthreads();
  float S1=r1[0]+r1[1]+r1[2]+r1[3];
  float S2=r2[0]+r2[1]+r2[2]+r2[3];
  float S3=r3[0]+r3[1]+r3[2]+r3[3];
  float mu  = S1*(1.f/512.f);
  float var = S2*(1.f/512.f) - mu*mu;
  float rstd= rsqrtf(var + 1e-5f);
  float lr  = 0.01f/(1.f+__expf(-S3));
  tv[tid]     = ((v0-mu)*rstd - pr[tid])*lr;
  tv[tid+256] = ((v1-mu)*rstd - pr[tid+256])*lr;
}

// ---------------- 9. dout = erb @ wob^T (MFMA) -> doh + dot bf16 ----------------
__global__ __launch_bounds__(256) void k_gemm_dout(const short* __restrict__ erb,
    const short* __restrict__ wob, short* __restrict__ doh, short* __restrict__ dot){
  __shared__ __attribute__((aligned(16))) short as[64][LBK], bs[64][LBK];
  int r0=blockIdx.x<<6, h=blockIdx.y;
  f32x4 acc[4];
  #pragma unroll
  for(int nb=0;nb<4;nb++) acc[nb]=(f32x4){0.f,0.f,0.f,0.f};
  gemm64(erb+(size_t)r0*512, 512, wob+(size_t)h*32768, 512, 8, as, bs, acc);
  int tid=threadIdx.x, w=tid>>6, lane=tid&63, lg=lane>>4, ln=lane&15;
  size_t bh=(size_t)(r0>>11)*8+h;
  int n0=(r0&2047)+w*16+lg*4;
  #pragma unroll
  for(int nb=0;nb<4;nb++){
    int e=nb*16+ln;
    short4 s4;
    s4.x=f2bf(acc[nb][0]); s4.y=f2bf(acc[nb][1]);
    s4.z=f2bf(acc[nb][2]); s4.w=f2bf(acc[nb][3]);
    doh[(bh*2048+n0  )*64+e]=s4.x;
    doh[(bh*2048+n0+1)*64+e]=s4.y;
    doh[(bh*2048+n0+2)*64+e]=s4.z;
    doh[(bh*2048+n0+3)*64+e]=s4.w;
    *(short4*)&dot[(bh*64+e)*2048+n0]=s4;
  }
}

// ---------------- 10. delta = sum_e dout*out ----------------
__global__ __launch_bounds__(256) void k_delta(const short* __restrict__ doh,
    const short* __restrict__ obb, float* __restrict__ delta){
  int rid = blockIdx.x*4 + (threadIdx.x>>6);
  int lane = threadIdx.x&63;
  if(rid >= B_*H_*NM_) return;
  int b = rid/(H_*NM_); int rem = rid - b*H_*NM_;
  int h = rem/NM_; int i = rem - h*NM_;
  float v = bf2f(doh[((size_t)(b*H_+h)*N_ + i)*DH_ + lane])
          * bf2f(obb[((size_t)(b*N_+i))*D_ + h*DH_ + lane]);
  v = wred64(v);
  if(lane==0) delta[((size_t)(b*H_+h))*N_ + i] = v;
}

// ---------------- 11. flash bwd dq: paired i-tiles + 2-way j-split ----------------
__global__ __launch_bounds__(256) void k_fa_dq(const short* __restrict__ qh,
    const short* __restrict__ kh, const short* __restrict__ vh,
    const short* __restrict__ kt, const short* __restrict__ doh,
    const float* __restrict__ lse, const float* __restrict__ delta,
    short* __restrict__ dqt, short* __restrict__ dqp1){
  int bh = blockIdx.x, y = blockIdx.y;
  int a    = (y<16)? y : 31-y;
  int half = (y<16)? 0 : 1;
  int itA = 2*a, itB = 2*a+1;
  const short* qhb = qh + (size_t)bh*N_*DH_;
  const short* khb = kh + (size_t)bh*N_*DH_;
  const short* vhb = vh + (size_t)bh*N_*DH_;
  const short* ktb = kt + (size_t)bh*DH_*N_;
  const short* dohb= doh+ (size_t)bh*N_*DH_;
  __shared__ __attribute__((aligned(16))) short ks[64][LBK], vs[64][LBK], kts[64][LBK];
  __shared__ __attribute__((aligned(16))) short psb[2][4][16][LBK];
  int tid=threadIdx.x, w=tid>>6, lane=tid&63, lg=lane>>4, ln=lane&15;
  bf16x8 aq[2][2], ad[2][2];
  float Lr[2][4], dl[2][4];
  #pragma unroll
  for(int sd=0;sd<2;sd++){
    int i0=(sd?itB:itA)<<6;
    #pragma unroll
    for(int s=0;s<2;s++){
      aq[sd][s]=*(const bf16x8*)&qhb[(size_t)(i0+w*16+ln)*DH_+32*s+lg*8];
      ad[sd][s]=*(const bf16x8*)&dohb[(size_t)(i0+w*16+ln)*DH_+32*s+lg*8];
    }
    #pragma unroll
    for(int r=0;r<4;r++){
      int ii=i0+w*16+lg*4+r;
      Lr[sd][r]=lse[(size_t)bh*N_+ii];
      dl[sd][r]=(ii<NM_)?delta[(size_t)bh*N_+ii]:0.f;
    }
  }
  f32x4 acc[2][4];
  #pragma unroll
  for(int sd=0;sd<2;sd++)
    #pragma unroll
    for(int nb=0;nb<4;nb++) acc[sd][nb]=(f32x4){0.f,0.f,0.f,0.f};
  int4 ka0,ka1,va0,va1,ta0,ta1;
  tload(khb+(size_t)half*64*DH_, DH_, tid, ka0,ka1);
  tload(vhb+(size_t)half*64*DH_, DH_, tid, va0,va1);
  tload(ktb+half*64, N_, tid, ta0,ta1);
  for(int jt=half;jt<=itB;jt+=2){
    int j0=jt<<6;
    bool actA = (jt<=itA);
    __syncthreads();
    twrite(ks, tid, ka0,ka1);
    twrite(vs, tid, va0,va1);
    twrite(kts, tid, ta0,ta1);
    if(jt+2<=itB){
      tload(khb+(size_t)(jt+2)*64*DH_, DH_, tid, ka0,ka1);
      tload(vhb+(size_t)(jt+2)*64*DH_, DH_, tid, va0,va1);
      tload(ktb+(jt+2)*64, N_, tid, ta0,ta1);
    }
    __syncthreads();
    #pragma unroll
    for(int nb=0;nb<4;nb++){
      f32x4 z0={0.f,0.f,0.f,0.f}, zd0={0.f,0.f,0.f,0.f};
      f32x4 z1={0.f,0.f,0.f,0.f}, zd1={0.f,0.f,0.f,0.f};
      __builtin_amdgcn_s_setprio(1);
      #pragma unroll
      for(int s=0;s<2;s++){
        bf16x8 bk=*(const bf16x8*)&ks[nb*16+ln][32*s+lg*8];
        bf16x8 bv=*(const bf16x8*)&vs[nb*16+ln][32*s+lg*8];
        z0 = MFMA_B16(aq[0][s], bk, z0);
        zd0= MFMA_B16(ad[0][s], bv, zd0);
        z1 = MFMA_B16(aq[1][s], bk, z1);
        zd1= MFMA_B16(ad[1][s], bv, zd1);
      }
      __builtin_amdgcn_s_setprio(0);
      #pragma unroll
      for(int sd=0;sd<2;sd++){
        if(sd==0 && !actA) continue;
        int it_ = sd? itB : itA;
        f32x4 z  = sd? z1 : z0;
        f32x4 zd = sd? zd1: zd0;
        if((jt==it_)||(it_==31)){
          int i0=it_<<6;
          #pragma unroll
          for(int r=0;r<4;r++){
            int ii=i0+w*16+lg*4+r, jj=j0+nb*16+ln;
            float pv=__expf(z[r]*SCALE_F - Lr[sd][r]);
            float dsv=SCALE_F*pv*(zd[r]-dl[sd][r]);
            if(jj>ii || ii>=NM_ || jj>=NM_) dsv=0.f;
            psb[sd][w][lg*4+r][ln+16*nb]=f2bf(dsv);
          }
        } else {
          #pragma unroll
          for(int r=0;r<4;r++){
            float pv=__expf(z[r]*SCALE_F - Lr[sd][r]);
            psb[sd][w][lg*4+r][ln+16*nb]=f2bf(SCALE_F*pv*(zd[r]-dl[sd][r]));
          }
        }
      }
    }
    lds_fence();
    __builtin_amdgcn_s_setprio(1);
    #pragma unroll
    for(int nb=0;nb<4;nb++){
      #pragma unroll
      for(int s=0;s<2;s++){
        bf16x8 bkt = *(const bf16x8*)&kts[nb*16+ln][32*s+lg*8];
        bf16x8 pa1 = *(const bf16x8*)&psb[1][w][ln][32*s+lg*8];
        acc[1][nb]=MFMA_B16(pa1,bkt,acc[1][nb]);
        if(actA){
          bf16x8 pa0 = *(const bf16x8*)&psb[0][w][ln][32*s+lg*8];
          acc[0][nb]=MFMA_B16(pa0,bkt,acc[0][nb]);
        }
      }
    }
    __builtin_amdgcn_s_setprio(0);
    lds_fence();
  }
  short* dst = half? dqp1 : dqt;
  #pragma unroll
  for(int sd=0;sd<2;sd++){
    int i0=(sd?itB:itA)<<6;
    #pragma unroll
    for(int nb=0;nb<4;nb++){
      short4 s4;
      s4.x=f2bf(acc[sd][nb][0]); s4.y=f2bf(acc[sd][nb][1]);
      s4.z=f2bf(acc[sd][nb][2]); s4.w=f2bf(acc[sd][nb][3]);
      *(short4*)&dst[((size_t)bh*64 + nb*16+ln)*2048 + i0+w*16+lg*4]=s4;
    }
  }
}

// dqt += dqp1 (bf16, deterministic)
__global__ __launch_bounds__(256) void k_dqred(short* __restrict__ dqt,
    const short* __restrict__ dqp1){
  size_t i = ((size_t)blockIdx.x*256 + threadIdx.x)*8;
  int4 a = *(const int4*)&dqt[i];
  int4 b = *(const int4*)&dqp1[i];
  short* pa=(short*)&a; const short* pb=(const short*)&b;
  short out[8];
  #pragma unroll
  for(int k=0;k<8;k++) out[k]=f2bf(bf2f(pa[k])+bf2f(pb[k]));
  *(int4*)&dqt[i] = *(int4*)out;
}

// ---------------- 12. flash bwd dk,dv: paired j-tiles + 2-way i-split ----------------
__global__ __launch_bounds__(256) void k_fa_dkv(const short* __restrict__ kh,
    const short* __restrict__ vh, const short* __restrict__ qh,
    const short* __restrict__ qt, const short* __restrict__ doh,
    const short* __restrict__ dot,
    const float* __restrict__ lse, const float* __restrict__ delta,
    short* __restrict__ dkt, short* __restrict__ dvt,
    short* __restrict__ dkp1, short* __restrict__ dvp1){
  int bh = blockIdx.x, y = blockIdx.y;
  int a    = (y<16)? y : 31-y;
  int half = (y<16)? 0 : 1;
  int jtA = 2*a, jtB = 2*a+1;
  int j0A = jtA<<6, j0B = jtB<<6;
  const short* khb = kh + (size_t)bh*N_*DH_;
  const short* vhb = vh + (size_t)bh*N_*DH_;
  const short* qhb = qh + (size_t)bh*N_*DH_;
  const short* qtb = qt + (size_t)bh*DH_*N_;
  const short* dohb= doh+ (size_t)bh*N_*DH_;
  const short* dotb= dot+ (size_t)bh*DH_*N_;
  __shared__ __attribute__((aligned(16))) short qs[64][LBK], dos[64][LBK], qts[64][LBK], dots[64][LBK];
  __shared__ __attribute__((aligned(16))) short psv[2][4][16][LBK], psk[2][4][16][LBK];
  __shared__ float Ls[64], dls[64];
  int tid=threadIdx.x, w=tid>>6, lane=tid&63, lg=lane>>4, ln=lane&15;
  bf16x8 akf[2][2], avf[2][2];
  #pragma unroll
  for(int sd=0;sd<2;sd++){
    int j0=(sd?jtB:jtA)<<6;
    #pragma unroll
    for(int s=0;s<2;s++){
      akf[sd][s]=*(const bf16x8*)&khb[(size_t)(j0+w*16+ln)*DH_+32*s+lg*8];
      avf[sd][s]=*(const bf16x8*)&vhb[(size_t)(j0+w*16+ln)*DH_+32*s+lg*8];
    }
  }
  f32x4 accv[2][4], acck[2][4];
  #pragma unroll
  for(int sd=0;sd<2;sd++)
    #pragma unroll
    for(int nb=0;nb<4;nb++){
      accv[sd][nb]=(f32x4){0.f,0.f,0.f,0.f};
      acck[sd][nb]=(f32x4){0.f,0.f,0.f,0.f};
    }
  int it0 = jtA + half;
  int4 qa0,qa1,da0,da1,qta0,qta1,dta0,dta1;
  float Lnx=0.f, dlnx=0.f;
  {
    int ip = it0<<6;
    tload(qhb+(size_t)ip*DH_, DH_, tid, qa0,qa1);
    tload(dohb+(size_t)ip*DH_, DH_, tid, da0,da1);
    tload(qtb+ip, N_, tid, qta0,qta1);
    tload(dotb+ip, N_, tid, dta0,dta1);
    if(tid<64){
      int ii=ip+tid;
      Lnx=lse[(size_t)bh*N_+ii];
      dlnx=(ii<NM_)?delta[(size_t)bh*N_+ii]:0.f;
    }
  }
  for(int it=it0; it<32; it+=2){
    int i0=it<<6;
    bool actB = (it>=jtB);
    __syncthreads();
    twrite(qs, tid, qa0,qa1);
    twrite(dos, tid, da0,da1);
    twrite(qts, tid, qta0,qta1);
    twrite(dots, tid, dta0,dta1);
    if(tid<64){ Ls[tid]=Lnx; dls[tid]=dlnx; }
    if(it+2<32){
      int i1=(it+2)<<6;
      tload(qhb+(size_t)i1*DH_, DH_, tid, qa0,qa1);
      tload(dohb+(size_t)i1*DH_, DH_, tid, da0,da1);
      tload(qtb+i1, N_, tid, qta0,qta1);
      tload(dotb+i1, N_, tid, dta0,dta1);
      if(tid<64){
        int ii=i1+tid;
        Lnx=lse[(size_t)bh*N_+ii];
        dlnx=(ii<NM_)?delta[(size_t)bh*N_+ii]:0.f;
      }
    }
    __syncthreads();
    #pragma unroll
    for(int nb=0;nb<4;nb++){
      f32x4 z0={0.f,0.f,0.f,0.f}, zd0={0.f,0.f,0.f,0.f};
      f32x4 z1={0.f,0.f,0.f,0.f}, zd1={0.f,0.f,0.f,0.f};
      __builtin_amdgcn_s_setprio(1);
      #pragma unroll
      for(int s=0;s<2;s++){
        bf16x8 bq=*(const bf16x8*)&qs[nb*16+ln][32*s+lg*8];
        bf16x8 bd=*(const bf16x8*)&dos[nb*16+ln][32*s+lg*8];
        z0 = MFMA_B16(akf[0][s], bq, z0);
        zd0= MFMA_B16(avf[0][s], bd, zd0);
        z1 = MFMA_B16(akf[1][s], bq, z1);
        zd1= MFMA_B16(avf[1][s], bd, zd1);
      }
      __builtin_amdgcn_s_setprio(0);
      float Lc=Ls[nb*16+ln], dlc=dls[nb*16+ln];
      int ii=i0+nb*16+ln;
      #pragma unroll
      for(int sd=0;sd<2;sd++){
        if(sd==1 && !actB) continue;
        int jt_ = sd? jtB : jtA;
        int j0_ = sd? j0B : j0A;
        f32x4 z  = sd? z1 : z0;
        f32x4 zd = sd? zd1: zd0;
        if((it==jt_)||(it==31)){
          #pragma unroll
          for(int r=0;r<4;r++){
            int jj=j0_+w*16+lg*4+r;
            float pv=__expf(z[r]*SCALE_F - Lc);
            bool msk=(jj>ii)||(ii>=NM_)||(jj>=NM_);
            if(msk) pv=0.f;
            float ds = msk?0.f: SCALE_F*pv*(zd[r]-dlc);
            psv[sd][w][lg*4+r][ln+16*nb]=f2bf(pv);
            psk[sd][w][lg*4+r][ln+16*nb]=f2bf(ds);
          }
        } else {
          #pragma unroll
          for(int r=0;r<4;r++){
            float pv=__expf(z[r]*SCALE_F - Lc);
            psv[sd][w][lg*4+r][ln+16*nb]=f2bf(pv);
            psk[sd][w][lg*4+r][ln+16*nb]=f2bf(SCALE_F*pv*(zd[r]-dlc));
          }
        }
      }
    }
    lds_fence();
    __builtin_amdgcn_s_setprio(1);
    #pragma unroll
    for(int nb=0;nb<4;nb++){
      #pragma unroll
      for(int s=0;s<2;s++){
        bf16x8 bd = *(const bf16x8*)&dots[nb*16+ln][32*s+lg*8];
        bf16x8 bq = *(const bf16x8*)&qts[nb*16+ln][32*s+lg*8];
        bf16x8 pa0 = *(const bf16x8*)&psv[0][w][ln][32*s+lg*8];
        accv[0][nb]=MFMA_B16(pa0,bd,accv[0][nb]);
        bf16x8 pk0 = *(const bf16x8*)&psk[0][w][ln][32*s+lg*8];
        acck[0][nb]=MFMA_B16(pk0,bq,acck[0][nb]);
        if(actB){
          bf16x8 pa1 = *(const bf16x8*)&psv[1][w][ln][32*s+lg*8];
          accv[1][nb]=MFMA_B16(pa1,bd,accv[1][nb]);
          bf16x8 pk1 = *(const bf16x8*)&psk[1][w][ln][32*s+lg*8];
          acck[1][nb]=MFMA_B16(pk1,bq,acck[1][nb]);
        }
      }
    }
    __builtin_amdgcn_s_setprio(0);
    lds_fence();
  }
  short* dvd = half? dvp1 : dvt;
  short* dkd = half? dkp1 : dkt;
  #pragma unroll
  for(int sd=0;sd<2;sd++){
    int j0=(sd?jtB:jtA)<<6;
    #pragma unroll
    for(int nb=0;nb<4;nb++){
      int e=nb*16+ln, n0=j0+w*16+lg*4;
      short4 s4;
      s4.x=f2bf(accv[sd][nb][0]); s4.y=f2bf(accv[sd][nb][1]);
      s4.z=f2bf(accv[sd][nb][2]); s4.w=f2bf(accv[sd][nb][3]);
      *(short4*)&dvd[((size_t)bh*64+e)*2048 + n0]=s4;
      s4.x=f2bf(acck[sd][nb][0]); s4.y=f2bf(acck[sd][nb][1]);
      s4.z=f2bf(acck[sd][nb][2]); s4.w=f2bf(acck[sd][nb][3]);
      *(short4*)&dkd[((size_t)bh*64+e)*2048 + n0]=s4;
    }
  }
}

// dkt += dkp1; dvt += dvp1
__global__ __launch_bounds__(256) void k_dkvred(short* __restrict__ dkt,
    short* __restrict__ dvt, const short* __restrict__ dkp1,
    const short* __restrict__ dvp1){
  int bid = blockIdx.x;
  short* dst; const short* src;
  if(bid<1024){ dst=dkt; src=dkp1; } else { dst=dvt; src=dvp1; bid-=1024; }
  size_t i = ((size_t)bid*256 + threadIdx.x)*8;
  int4 a = *(const int4*)&dst[i];
  int4 b = *(const int4*)&src[i];
  short* pa=(short*)&a; const short* pb=(const short*)&b;
  short out[8];
  #pragma unroll
  for(int k=0;k<8;k++) out[k]=f2bf(bf2f(pa[k])+bf2f(pb[k]));
  *(int4*)&dst[i] = *(int4*)out;
}

// ---------------- 13. weight grads (MFMA, split-K=8) ----------------
__global__ __launch_bounds__(256) void k_gemm_wgq(const short* __restrict__ tt,
    const short* __restrict__ g, float* __restrict__ par){
  __shared__ __attribute__((aligned(16))) short as[64][LBK], bs[64][LBK];
  int dt=blockIdx.x, h=blockIdx.y, sp=blockIdx.z;
  int b=sp>>2, n0b=(sp&3)*512;
  f32x4 acc[4];
  #pragma unroll
  for(int nb=0;nb<4;nb++) acc[nb]=(f32x4){0.f,0.f,0.f,0.f};
  gemm64(tt + (size_t)(dt*64)*4096 + sp*512, 4096,
         g  + ((size_t)(b*8+h)*64)*2048 + n0b, 2048, 8, as, bs, acc);
  int tid=threadIdx.x, w=tid>>6, lane=tid&63, lg=lane>>4, ln=lane&15;
  int row=w*16+lg*4;
  #pragma unroll
  for(int nb=0;nb<4;nb++)
    #pragma unroll
    for(int r=0;r<4;r++)
      par[(size_t)sp*262144 + (size_t)h*32768 + (size_t)(dt*64+row+r)*64 + nb*16+ln]=acc[nb][r];
}

__global__ __launch_bounds__(256) void k_gemm_wgo(const short* __restrict__ outt,
    const short* __restrict__ ert, float* __restrict__ par){
  __shared__ __attribute__((aligned(16))) short as[64][LBK], bs[64][LBK];
  int ct=blockIdx.x, h=blockIdx.y, sp=blockIdx.z;
  f32x4 acc[4];
  #pragma unroll
  for(int nb=0;nb<4;nb++) acc[nb]=(f32x4){0.f,0.f,0.f,0.f};
  gemm64(outt + (size_t)(h*64)*4096 + sp*512, 4096,
         ert  + (size_t)(ct*64)*4096 + sp*512, 4096, 8, as, bs, acc);
  int tid=threadIdx.x, w=tid>>6, lane=tid&63, lg=lane>>4, ln=lane&15;
  int row=w*16+lg*4;
  #pragma unroll
  for(int nb=0;nb<4;nb++)
    #pragma unroll
    for(int r=0;r<4;r++)
      par[(size_t)sp*262144 + (size_t)h*32768 + (size_t)(row+r)*512 + ct*64+nb*16+ln]=acc[nb][r];
}

__global__ __launch_bounds__(256) void k_wred_direct(const float* __restrict__ par,
    float* __restrict__ dst){
  int idx = blockIdx.x*256 + threadIdx.x;
  float s=0.f;
  #pragma unroll
  for(int sp=0;sp<8;sp++) s += par[(size_t)sp*262144 + idx];
  dst[idx]=s;
}
__global__ __launch_bounds__(256) void k_wred_xv(const float* __restrict__ par,
    float* __restrict__ X0){
  int idx = blockIdx.x*256 + threadIdx.x;
  float s=0.f;
  #pragma unroll
  for(int sp=0;sp<8;sp++) s += par[(size_t)sp*262144 + idx];
  int h=idx>>15, rem=idx&32767, d=rem>>6, e=rem&63;
  X0[(size_t)h*32768 + (size_t)e*512 + d]=s;
}
__global__ __launch_bounds__(256) void k_wred_xo(const float* __restrict__ par,
    float* __restrict__ X0){
  int idx = blockIdx.x*256 + threadIdx.x;
  float s=0.f;
  #pragma unroll
  for(int sp=0;sp<8;sp++) s += par[(size_t)sp*262144 + idx];
  X0[262144 + idx]=s;
}

// ---------------- 14. Newton-Schulz fused (16 blocks x 1024 threads) ----------------
__global__ __launch_bounds__(1024) void k_ns_fused(const float* __restrict__ X0,
    float* __restrict__ dwv, float* __restrict__ dwo){
  __shared__ __attribute__((aligned(16))) short Xl[64][520];
  __shared__ __attribute__((aligned(16))) short Xt[512][72];
  __shared__ __attribute__((aligned(16))) short Al[64][72];
  __shared__ __attribute__((aligned(16))) short Bl[64][72];
  __shared__ float red[16];
  int m = blockIdx.x, tid=threadIdx.x, w=tid>>6, lane=tid&63, lg=lane>>4, ln=lane&15;
  int wr=w>>2, wc=w&3;
  const float* Xg = X0 + (size_t)m*32768;
  float ss=0.f;
  for(int kk=0;kk<32;kk++){ float v=Xg[kk*1024+tid]; ss+=v*v; }
  ss=wred64(ss);
  if(lane==0) red[w]=ss;
  __syncthreads();
  float tot=0.f;
  #pragma unroll
  for(int i=0;i<16;i++) tot+=red[i];
  float sc = 1.f/fmaxf(sqrtf(tot), 1e-7f);
  for(int kk=0;kk<32;kk++){
    int idx=kk*1024+tid; int rr=idx>>9, cc=idx&511;
    short v=f2bf(Xg[idx]*sc);
    Xl[rr][cc]=v; Xt[cc][rr]=v;
  }
  __syncthreads();
  for(int iter=0; iter<5; ++iter){
    f32x4 accA=(f32x4){0.f,0.f,0.f,0.f};
    #pragma unroll
    for(int kt=0;kt<16;kt++){
      bf16x8 a = *(const bf16x8*)&Xl[wr*16+ln][kt*32+lg*8];
      bf16x8 b = *(const bf16x8*)&Xl[wc*16+ln][kt*32+lg*8];
      accA=MFMA_B16(a,b,accA);
    }
    #pragma unroll
    for(int r=0;r<4;r++) Al[wr*16+lg*4+r][wc*16+ln]=f2bf(accA[r]);
    __syncthreads();
    f32x4 acc2=(f32x4){0.f,0.f,0.f,0.f};
    #pragma unroll
    for(int s=0;s<2;s++){
      bf16x8 a = *(const bf16x8*)&Al[wr*16+ln][32*s+lg*8];
      bf16x8 b = *(const bf16x8*)&Al[wc*16+ln][32*s+lg*8];
      acc2=MFMA_B16(a,b,acc2);
    }
    #pragma unroll
    for(int r=0;r<4;r++)
      Bl[wr*16+lg*4+r][wc*16+ln]=f2bf(-4.775f*accA[r] + 2.0315f*acc2[r]);
    __syncthreads();
    int rg=(w&3)<<4, cg=(w>>2)<<7;
    f32x4 xn[8];
    #pragma unroll
    for(int nb=0;nb<8;nb++){
      xn[nb]=(f32x4){0.f,0.f,0.f,0.f};
      #pragma unroll
      for(int s=0;s<2;s++){
        bf16x8 a = *(const bf16x8*)&Bl[rg+ln][32*s+lg*8];
        bf16x8 b = *(const bf16x8*)&Xt[cg+nb*16+ln][32*s+lg*8];
        xn[nb]=MFMA_B16(a,b,xn[nb]);
      }
      #pragma unroll
      for(int r=0;r<4;r++)
        xn[nb][r] += 3.4445f*bf2f(Xl[rg+lg*4+r][cg+nb*16+ln]);
    }
    __syncthreads();
    if(iter<4){
      #pragma unroll
      for(int nb=0;nb<8;nb++){
        int d=cg+nb*16+ln, row0=rg+lg*4;
        short4 s4;
        s4.x=f2bf(xn[nb][0]); s4.y=f2bf(xn[nb][1]);
        s4.z=f2bf(xn[nb][2]); s4.w=f2bf(xn[nb][3]);
        Xl[row0  ][d]=s4.x; Xl[row0+1][d]=s4.y;
        Xl[row0+2][d]=s4.z; Xl[row0+3][d]=s4.w;
        *(short4*)&Xt[d][row0]=s4;
      }
      __syncthreads();
    } else {
      #pragma unroll
      for(int nb=0;nb<8;nb++){
        int d=cg+nb*16+ln, row0=rg+lg*4;
        #pragma unroll
        for(int r=0;r<4;r++){
          float v=xn[nb][r];
          int e=row0+r;
          if(m<8) dwv[(size_t)m*32768 + (size_t)d*64 + e]=v;
          else    dwo[(size_t)(m-8)*32768 + (size_t)e*512 + d]=v;
        }
      }
    }
  }
}

// ---------------- launch ----------------
extern "C" void kernel_launch(void* const* d_in, const int* in_sizes, int n_in,
                              void* d_out, int out_size, void* d_ws, size_t ws_size,
                              hipStream_t stream) {
  const float* tokens=(const float*)d_in[0];
  const float* rmsw =(const float*)d_in[1];
  const float* wq   =(const float*)d_in[2];
  const float* wk   =(const float*)d_in[3];
  const float* wv   =(const float*)d_in[4];
  const float* wo   =(const float*)d_in[5];
  const float* lrw  =(const float*)d_in[6];
  const float* tvw  =(const float*)d_in[7];
  float* out = (float*)d_out;
  float* ws  = (float*)d_ws;

  short* tb   = (short*)(ws);            // [4160][512] bf16 (pad rows zero)
  short* tt   = (short*)(ws + 1064960);  // [512][4096]
  short* qh   = (short*)(ws + 2113536);  // [16bh][2048][64]
  short* kh   = (short*)(ws + 3162112);
  short* vh   = (short*)(ws + 4210688);
  short* qt   = (short*)(ws + 5259264);  // [16bh][64][2048]
  short* kt   = (short*)(ws + 6307840);
  short* vt   = (short*)(ws + 7356416);
  float* er_  = ws + 8404992;            // f32 [4096][512]
  float* op0  = ws + 8404992;            // fwd partial 0 (dead before er_)
  short* dqp1 = (short*)(ws + 8404992);  // bwd partials (after er_ dead)
  short* dkp1 = (short*)(ws + 8404992);
  short* dvp1 = (short*)(ws + 9453568);
  short* obb  = (short*)(ws + 10502144); // bf16 [4096][512]
  short* outt = (short*)(ws + 11550720); // bf16 [512][4096]
  short* erb  = (short*)(ws + 12599296);
  short* ert  = (short*)(ws + 13647872);
  short* doh  = (short*)(ws + 14696448); // [16bh][2048][64]
  short* dot  = (short*)(ws + 15745024); // [16bh][64][2048]
  float* par_ = ws + 14696448;           // aliases doh+dot (dead before wgrad)
  float* op1  = ws + 14696448;           // fwd partial 1 (dead before doh/dot)
  short* dqt  = (short*)(ws + 16793600); // [16bh][64][2048]
  float* mlb  = ws + 16793600;           // fwd m/l partials (dead before dqt)
  short* dkt  = (short*)(ws + 17842176);
  short* dvt  = (short*)(ws + 18890752);
  short* wqt  = (short*)(ws + 19939328); // [8h][64][512]
  short* wkt  = (short*)(ws + 20070400);
  short* wvt  = (short*)(ws + 20201472);
  short* wob  = (short*)(ws + 20332544); // [512 he][512 d]
  short* wot  = (short*)(ws + 20463616); // [512 d][512 he]
  short* tvwb = (short*)(ws + 20594688); // [512 o][512 d]
  float* lse_ = ws + 20725760;
  float* dlt_ = ws + 20758528;
  float* X0_  = ws + 20791296;

  float* OUT_PRED = out;
  float* OUT_DWQ  = out + 2097152;
  float* OUT_DWK  = out + 2359296;
  float* OUT_DWV  = out + 2621440;
  float* OUT_DWO  = out + 2883584;

  k_rmsnorm<<<4160,256,0,stream>>>(tokens, rmsw, tb);
  k_wprep<<<272,256,0,stream>>>(wq,wk,wv,wo,tvw, wqt,wkt,wvt,wob,wot,tvwb);
  k_gemm_qkv<<<dim3(64,24),256,0,stream>>>(tb, wqt,wkt,wvt, qh,kh,vh, qt,kt,vt);
  k_fa_fwd<<<dim3(16,32),256,0,stream>>>(qh, kh, vt, op0, op1, mlb);
  k_fa_merge<<<8192,256,0,stream>>>(op0, op1, mlb, obb, lse_);
  k_gemm_pred<<<dim3(64,8),256,0,stream>>>(obb, wot, OUT_PRED);

  if(out_size < 3145728) return;   // forward-only variant

  k_trans_b<<<dim3(64,8),256,0,stream>>>(tb, tt);
  k_gemm_tv<<<dim3(64,8),256,0,stream>>>(tb, tvwb, er_);
  k_lnerr<<<4094,256,0,stream>>>(er_, tb, OUT_PRED, lrw);
  k_trans_f<<<dim3(64,8),256,0,stream>>>(er_, erb, ert);
  k_gemm_dout<<<dim3(64,8),256,0,stream>>>(erb, wob, doh, dot);
  k_delta<<<8188,256,0,stream>>>(doh, obb, dlt_);
  k_fa_dq<<<dim3(16,32),256,0,stream>>>(qh, kh, vh, kt, doh, lse_, dlt_, dqt, dqp1);
  k_dqred<<<1024,256,0,stream>>>(dqt, dqp1);
  k_fa_dkv<<<dim3(16,32),256,0,stream>>>(kh, vh, qh, qt, doh, dot, lse_, dlt_,
                                         dkt, dvt, dkp1, dvp1);
  k_dkvred<<<2048,256,0,stream>>>(dkt, dvt, dkp1, dvp1);
  k_trans_b<<<dim3(64,8),256,0,stream>>>(obb, outt);

  k_gemm_wgq<<<dim3(8,8,8),256,0,stream>>>(tt, dqt, par_);
  k_wred_direct<<<1024,256,0,stream>>>(par_, OUT_DWQ);
  k_gemm_wgq<<<dim3(8,8,8),256,0,stream>>>(tt, dkt, par_);
  k_wred_direct<<<1024,256,0,stream>>>(par_, OUT_DWK);
  k_gemm_wgq<<<dim3(8,8,8),256,0,stream>>>(tt, dvt, par_);
  k_wred_xv<<<1024,256,0,stream>>>(par_, X0_);
  k_gemm_wgo<<<dim3(8,8,8),256,0,stream>>>(outt, ert, par_);
  k_wred_xo<<<1024,256,0,stream>>>(par_, X0_);

  k_ns_fused<<<16,1024,0,stream>>>(X0_, OUT_DWV, OUT_DWO);
}

// Round 11
// 311.550 us; speedup vs baseline: 1.1328x; 1.1328x over previous
//
#include <hip/hip_runtime.h>
#include <float.h>
#include <math.h>

// ---------------- problem constants ----------------
#define B_   2
#define N_   2048
#define D_   512
#define H_   8
#define DH_  64
#define NM_  2047            // n-1
#define SCALE_F 0.125f       // 64^-0.5
#define LBK 72               // LDS row pad (bf16 tiles), 144B: 16B-aligned rows

typedef __attribute__((ext_vector_type(8))) short bf16x8;
typedef __attribute__((ext_vector_type(4))) float f32x4;
#define MFMA_B16(a,b,c) __builtin_amdgcn_mfma_f32_16x16x32_bf16(a,b,c,0,0,0)

__device__ __forceinline__ short f2bf(float f){
  unsigned u = __float_as_uint(f);
  unsigned r = u + 0x7fffu + ((u>>16)&1u);
  return (short)(r>>16);
}
__device__ __forceinline__ float bf2f(short s){
  return __uint_as_float(((unsigned)(unsigned short)s)<<16);
}
__device__ __forceinline__ void lds_fence(){
  asm volatile("s_waitcnt lgkmcnt(0)" ::: "memory");
  __builtin_amdgcn_sched_barrier(0);
}
// load a 64x64 bf16 tile into regs (2 int4 per thread); pairs with twrite
__device__ __forceinline__ void tload(const short* __restrict__ src, size_t stride,
                                      int tid, int4& r0, int4& r1){
  int rr = tid>>2, cc = (tid&3)<<4;
  r0 = *(const int4*)&src[(size_t)rr*stride + cc];
  r1 = *(const int4*)&src[(size_t)rr*stride + cc + 8];
}
__device__ __forceinline__ void twrite(short (*dst)[LBK], int tid,
                                       const int4& r0, const int4& r1){
  int rr = tid>>2, cc = (tid&3)<<4;
  *(int4*)&dst[rr][cc]   = r0;
  *(int4*)&dst[rr][cc+8] = r1;
}
__device__ __forceinline__ float wred64(float v){
  #pragma unroll
  for(int off=32; off; off>>=1) v += __shfl_down(v, off, 64);
  return v;
}

// 64x64 MFMA GEMM mainloop with register-prefetch double buffering (2-phase)
__device__ __forceinline__ void gemm64(const short* __restrict__ A, size_t lda,
    const short* __restrict__ Bt, size_t ldb, int nk,
    short (*as)[LBK], short (*bs)[LBK], f32x4* acc){
  int tid=threadIdx.x, w=tid>>6, lane=tid&63, lg=lane>>4, ln=lane&15;
  int4 a0,a1,b0,b1;
  tload(A, lda, tid, a0,a1);
  tload(Bt, ldb, tid, b0,b1);
  for(int kt=0;kt<nk;++kt){
    __syncthreads();
    twrite(as, tid, a0,a1);
    twrite(bs, tid, b0,b1);
    if(kt+1<nk){
      tload(A +(size_t)(kt+1)*64, lda, tid, a0,a1);
      tload(Bt+(size_t)(kt+1)*64, ldb, tid, b0,b1);
    }
    __syncthreads();
    __builtin_amdgcn_s_setprio(1);
    #pragma unroll
    for(int s=0;s<2;s++){
      bf16x8 a = *(const bf16x8*)&as[w*16+ln][32*s+lg*8];
      #pragma unroll
      for(int nb=0;nb<4;nb++){
        bf16x8 b = *(const bf16x8*)&bs[nb*16+ln][32*s+lg*8];
        acc[nb]=MFMA_B16(a,b,acc[nb]);
      }
    }
    __builtin_amdgcn_s_setprio(0);
  }
}

// ---------------- 1. RMSNorm -> tb (bf16, padded to 4160 rows) ----------------
__global__ __launch_bounds__(256) void k_rmsnorm(const float* __restrict__ tok,
    const float* __restrict__ w, short* __restrict__ tb){
  int row = blockIdx.x;
  int tid = threadIdx.x;
  if(row>=4096){ tb[(size_t)row*D_+tid]=0; tb[(size_t)row*D_+tid+256]=0; return; }
  const float* x = tok + (size_t)row*D_;
  float v0 = x[tid], v1 = x[tid+256];
  float s = v0*v0 + v1*v1;
  s = wred64(s);
  __shared__ float red[4];
  if((tid&63)==0) red[tid>>6] = s;
  __syncthreads();
  float tot = red[0]+red[1]+red[2]+red[3];
  float sc = rsqrtf(tot*(1.f/512.f) + 1.1920929e-7f);
  tb[(size_t)row*D_+tid]     = f2bf(v0*sc*w[tid]);
  tb[(size_t)row*D_+tid+256] = f2bf(v1*sc*w[tid+256]);
}

// ---------------- 2. weight prep ----------------
__global__ __launch_bounds__(256) void k_wprep(const float* __restrict__ wq,
    const float* __restrict__ wk, const float* __restrict__ wv,
    const float* __restrict__ wo, const float* __restrict__ tvw,
    short* __restrict__ wqt, short* __restrict__ wkt, short* __restrict__ wvt,
    short* __restrict__ wob, short* __restrict__ wot, short* __restrict__ tvwb){
  __shared__ short l[64][66];
  int bx=blockIdx.x, tid=threadIdx.x;
  if(bx<192){
    const float* w = (bx<64)? wq : (bx<128)? wk : wv;
    short* wt      = (bx<64)? wqt: (bx<128)? wkt: wvt;
    int lb=bx&63, h=lb>>3, d0=(lb&7)*64;
    for(int kk=0;kk<16;kk++){
      int idx=kk*256+tid, rr=idx>>6, cc=idx&63;
      l[cc][rr] = f2bf(w[((size_t)h*512 + d0+rr)*64 + cc]);
    }
    __syncthreads();
    for(int kk=0;kk<16;kk++){
      int idx=kk*256+tid, rr=idx>>6, cc=idx&63;
      wt[((size_t)h*64+rr)*512 + d0+cc] = l[rr][cc];
    }
  } else if(bx<256){
    int lb=bx-192, r0=(lb>>3)*64, c0=(lb&7)*64;
    for(int kk=0;kk<16;kk++){
      int idx=kk*256+tid, rr=idx>>6, cc=idx&63;
      l[cc][rr] = f2bf(wo[(size_t)(r0+rr)*512 + c0+cc]);
    }
    __syncthreads();
    for(int kk=0;kk<16;kk++){
      int idx=kk*256+tid, rr=idx>>6, cc=idx&63;
      wot[(size_t)(c0+rr)*512 + r0+cc] = l[rr][cc];
    }
  } else if(bx<264){
    size_t base=(size_t)(bx-256)*32768;
    for(int kk=0;kk<128;kk++) wob[base+kk*256+tid]=f2bf(wo[base+kk*256+tid]);
  } else {
    size_t base=(size_t)(bx-264)*32768;
    for(int kk=0;kk<128;kk++) tvwb[base+kk*256+tid]=f2bf(tvw[base+kk*256+tid]);
  }
}

// ---------------- 3. transposes (4096x512) ----------------
__global__ __launch_bounds__(256) void k_trans_b(const short* __restrict__ in,
    short* __restrict__ outt){
  __shared__ short l[64][66];
  int r0=blockIdx.x<<6, c0=blockIdx.y<<6, tid=threadIdx.x;
  for(int kk=0;kk<16;kk++){
    int idx=kk*256+tid, rr=idx>>6, cc=idx&63;
    l[cc][rr]=in[(size_t)(r0+rr)*512 + c0+cc];
  }
  __syncthreads();
  for(int kk=0;kk<16;kk++){
    int idx=kk*256+tid, rr=idx>>6, cc=idx&63;
    outt[(size_t)(c0+rr)*4096 + r0+cc]=l[rr][cc];
  }
}
__global__ __launch_bounds__(256) void k_trans_f(const float* __restrict__ in,
    short* __restrict__ outn, short* __restrict__ outt){
  __shared__ short l[64][66];
  int r0=blockIdx.x<<6, c0=blockIdx.y<<6, tid=threadIdx.x;
  for(int kk=0;kk<16;kk++){
    int idx=kk*256+tid, rr=idx>>6, cc=idx&63;
    short v=f2bf(in[(size_t)(r0+rr)*512 + c0+cc]);
    outn[(size_t)(r0+rr)*512 + c0+cc]=v;
    l[cc][rr]=v;
  }
  __syncthreads();
  for(int kk=0;kk<16;kk++){
    int idx=kk*256+tid, rr=idx>>6, cc=idx&63;
    outt[(size_t)(c0+rr)*4096 + r0+cc]=l[rr][cc];
  }
}

// ---------------- 4. QKV projection (MFMA) ----------------
__global__ __launch_bounds__(256) void k_gemm_qkv(const short* __restrict__ tb,
    const short* __restrict__ wqt, const short* __restrict__ wkt, const short* __restrict__ wvt,
    short* __restrict__ qh, short* __restrict__ kh, short* __restrict__ vh,
    short* __restrict__ qt, short* __restrict__ kt, short* __restrict__ vt){
  __shared__ __attribute__((aligned(16))) short as[64][LBK], bs[64][LBK];
  int r0=blockIdx.x<<6, ct=blockIdx.y, which=ct>>3, h=ct&7;
  const short* Bt=(which==0?wqt:which==1?wkt:wvt)+(size_t)h*32768;
  f32x4 acc[4];
  #pragma unroll
  for(int nb=0;nb<4;nb++) acc[nb]=(f32x4){0.f,0.f,0.f,0.f};
  gemm64(tb+(size_t)r0*512, 512, Bt, 512, 8, as, bs, acc);
  short* on=(which==0?qh:which==1?kh:vh);
  short* ot=(which==0?qt:which==1?kt:vt);
  int tid=threadIdx.x, w=tid>>6, lane=tid&63, lg=lane>>4, ln=lane&15;
  size_t bh=(size_t)(r0>>11)*8+h;
  int n0=(r0&2047)+w*16+lg*4;
  #pragma unroll
  for(int nb=0;nb<4;nb++){
    int e=nb*16+ln;
    short4 s4;
    s4.x=f2bf(acc[nb][0]); s4.y=f2bf(acc[nb][1]);
    s4.z=f2bf(acc[nb][2]); s4.w=f2bf(acc[nb][3]);
    on[(bh*2048+n0  )*64+e]=s4.x;
    on[(bh*2048+n0+1)*64+e]=s4.y;
    on[(bh*2048+n0+2)*64+e]=s4.z;
    on[(bh*2048+n0+3)*64+e]=s4.w;
    *(short4*)&ot[(bh*64+e)*2048+n0]=s4;
  }
}

// ---------------- 5. flash attention forward (2-way j-split, partials) ----------------
__global__ __launch_bounds__(256) void k_fa_fwd(const short* __restrict__ qh,
    const short* __restrict__ kh, const short* __restrict__ vt,
    float* __restrict__ op0, float* __restrict__ op1, float* __restrict__ mlb){
  int bh = blockIdx.x, qq = blockIdx.y, half = blockIdx.z;
  int it = (qq<16)? (31-qq) : (qq-16);
  int i0 = it<<6;
  const short* qhb = qh + (size_t)bh*N_*DH_;
  const short* khb = kh + (size_t)bh*N_*DH_;
  const short* vtb = vt + (size_t)bh*DH_*N_;
  __shared__ __attribute__((aligned(16))) short ks[64][LBK], vts[64][LBK];
  __shared__ __attribute__((aligned(16))) short psb[4][16][LBK];
  int tid=threadIdx.x, w=tid>>6, lane=tid&63, lg=lane>>4, ln=lane&15;
  bf16x8 aq[2];
  #pragma unroll
  for(int s=0;s<2;s++)
    aq[s] = *(const bf16x8*)&qhb[(size_t)(i0+w*16+ln)*DH_ + 32*s + lg*8];
  f32x4 acc[4];
  float mrow[4], lrow[4];
  #pragma unroll
  for(int nb=0;nb<4;nb++) acc[nb]=(f32x4){0.f,0.f,0.f,0.f};
  #pragma unroll
  for(int r=0;r<4;r++){ mrow[r]=-FLT_MAX; lrow[r]=0.f; }
  int4 ka0,ka1,va0,va1;
  tload(khb+(size_t)half*64*DH_, DH_, tid, ka0,ka1);
  tload(vtb+half*64, N_, tid, va0,va1);
  for(int jt=half;jt<=it;jt+=2){
    int j0 = jt<<6;
    bool diag = (jt==it);
    __syncthreads();
    twrite(ks, tid, ka0,ka1);
    twrite(vts, tid, va0,va1);
    if(jt+2<=it){
      tload(khb+(size_t)(jt+2)*64*DH_, DH_, tid, ka0,ka1);
      tload(vtb+(jt+2)*64, N_, tid, va0,va1);
    }
    __syncthreads();
    f32x4 sv[4];
    __builtin_amdgcn_s_setprio(1);
    #pragma unroll
    for(int nb=0;nb<4;nb++){
      f32x4 z = {0.f,0.f,0.f,0.f};
      #pragma unroll
      for(int s=0;s<2;s++){
        bf16x8 bk = *(const bf16x8*)&ks[nb*16+ln][32*s + lg*8];
        z = MFMA_B16(aq[s], bk, z);
      }
      sv[nb]=z;
    }
    __builtin_amdgcn_s_setprio(0);
    int iiB = i0 + w*16 + lg*4;
    #pragma unroll
    for(int r=0;r<4;r++){
      int ii = iiB + r;
      float srow[4]; float mx = -FLT_MAX;
      if(diag){
        #pragma unroll
        for(int nb=0;nb<4;nb++){
          float x = sv[nb][r]*SCALE_F;
          if(j0+nb*16+ln > ii) x = -FLT_MAX;
          srow[nb]=x; mx=fmaxf(mx,x);
        }
      } else {
        #pragma unroll
        for(int nb=0;nb<4;nb++){
          float x = sv[nb][r]*SCALE_F;
          srow[nb]=x; mx=fmaxf(mx,x);
        }
      }
      mx=fmaxf(mx,__shfl_xor(mx,1)); mx=fmaxf(mx,__shfl_xor(mx,2));
      mx=fmaxf(mx,__shfl_xor(mx,4)); mx=fmaxf(mx,__shfl_xor(mx,8));
      float mn = fmaxf(mrow[r], mx);
      float rs = 0.f;
      #pragma unroll
      for(int nb=0;nb<4;nb++){
        float pv = __expf(srow[nb]-mn);
        psb[w][lg*4+r][ln+16*nb]=f2bf(pv); rs+=pv;
      }
      rs+=__shfl_xor(rs,1); rs+=__shfl_xor(rs,2);
      rs+=__shfl_xor(rs,4); rs+=__shfl_xor(rs,8);
      float corr = __expf(mrow[r]-mn);
      lrow[r]=lrow[r]*corr+rs; mrow[r]=mn;
      #pragma unroll
      for(int nb=0;nb<4;nb++) acc[nb][r]*=corr;
    }
    lds_fence();
    __builtin_amdgcn_s_setprio(1);
    #pragma unroll
    for(int nb=0;nb<4;nb++){
      #pragma unroll
      for(int s=0;s<2;s++){
        bf16x8 pa = *(const bf16x8*)&psb[w][ln][32*s + lg*8];
        bf16x8 bv = *(const bf16x8*)&vts[nb*16+ln][32*s + lg*8];
        acc[nb] = MFMA_B16(pa, bv, acc[nb]);
      }
    }
    __builtin_amdgcn_s_setprio(0);
    lds_fence();
  }
  float* op   = half? op1 : op0;
  float* marr = mlb + half*65536;
  float* larr = marr + 32768;
  #pragma unroll
  for(int r=0;r<4;r++){
    int ii = i0 + w*16 + lg*4 + r;
    size_t row = (size_t)bh*2048 + ii;
    #pragma unroll
    for(int nb=0;nb<4;nb++)
      op[row*64 + nb*16+ln] = acc[nb][r];
    if(ln==0){ marr[row]=mrow[r]; larr[row]=lrow[r]; }
  }
}

// merge two softmax partials -> obb bf16 + lse
__global__ __launch_bounds__(256) void k_fa_merge(const float* __restrict__ op0,
    const float* __restrict__ op1, const float* __restrict__ mlb,
    short* __restrict__ obb, float* __restrict__ lse){
  int row = blockIdx.x*4 + (threadIdx.x>>6);
  int lane = threadIdx.x&63;
  float m0 = mlb[row],        l0 = mlb[32768+row];
  float m1 = mlb[65536+row],  l1 = mlb[98304+row];
  float m  = fmaxf(m0,m1);
  float c0 = __expf(m0-m), c1 = __expf(m1-m);
  float l  = l0*c0 + l1*c1;
  float o  = (op0[(size_t)row*64+lane]*c0 + op1[(size_t)row*64+lane]*c1)/l;
  int bh = row>>11, i = row&2047, b = bh>>3, h = bh&7;
  obb[((size_t)(b*2048+i))*512 + h*64 + lane] = f2bf(o);
  if(lane==0) lse[row] = m + logf(l);
}

// ---------------- 6. pred = obb @ wot^T (MFMA), f32 out ----------------
__global__ __launch_bounds__(256) void k_gemm_pred(const short* __restrict__ obb,
    const short* __restrict__ wot, float* __restrict__ pred){
  __shared__ __attribute__((aligned(16))) short as[64][LBK], bs[64][LBK];
  int r0=blockIdx.x<<6, c0=blockIdx.y<<6;
  f32x4 acc[4];
  #pragma unroll
  for(int nb=0;nb<4;nb++) acc[nb]=(f32x4){0.f,0.f,0.f,0.f};
  gemm64(obb+(size_t)r0*512, 512, wot+(size_t)c0*512, 512, 8, as, bs, acc);
  int tid=threadIdx.x, w=tid>>6, lane=tid&63, lg=lane>>4, ln=lane&15;
  int row=r0+w*16+lg*4;
  #pragma unroll
  for(int nb=0;nb<4;nb++)
    #pragma unroll
    for(int r=0;r<4;r++)
      pred[(size_t)(row+r)*512 + c0+nb*16+ln]=acc[nb][r];
}

// ---------------- 7. tv = tb(shift+1) @ tvwb^T ----------------
__global__ __launch_bounds__(256) void k_gemm_tv(const short* __restrict__ tb,
    const short* __restrict__ tvwb, float* __restrict__ er){
  __shared__ __attribute__((aligned(16))) short as[64][LBK], bs[64][LBK];
  int r0=blockIdx.x<<6, c0=blockIdx.y<<6;
  f32x4 acc[4];
  #pragma unroll
  for(int nb=0;nb<4;nb++) acc[nb]=(f32x4){0.f,0.f,0.f,0.f};
  gemm64(tb+(size_t)(r0+1)*512, 512, tvwb+(size_t)c0*512, 512, 8, as, bs, acc);
  int tid=threadIdx.x, w=tid>>6, lane=tid&63, lg=lane>>4, ln=lane&15;
  int row=r0+w*16+lg*4;
  #pragma unroll
  for(int nb=0;nb<4;nb++)
    #pragma unroll
    for(int r=0;r<4;r++){
      float v=(((row+r)&2047)==2047)?0.f:acc[nb][r];
      er[(size_t)(row+r)*512 + c0+nb*16+ln]=v;
    }
}

// ---------------- 8. layernorm target + lr + error ----------------
__global__ __launch_bounds__(256) void k_lnerr(float* __restrict__ er,
    const short* __restrict__ tb, const float* __restrict__ pred,
    const float* __restrict__ lrw){
  int kr = blockIdx.x;
  int b = kr/NM_, n = kr-b*NM_;
  size_t row=(size_t)b*2048+n;
  float* tv = er + row*512;
  const short* tok = tb + row*512;
  const float* pr  = pred + row*512;
  int tid=threadIdx.x;
  float v0=tv[tid], v1=tv[tid+256];
  float s1=v0+v1, s2=v0*v0+v1*v1;
  float s3=bf2f(tok[tid])*lrw[tid] + bf2f(tok[tid+256])*lrw[tid+256];
  s1=wred64(s1); s2=wred64(s2); s3=wred64(s3);
  __shared__ float r1[4],r2[4],r3[4];
  if((tid&63)==0){ int w=tid>>6; r1[w]=s1; r2[w]=s2; r3[w]=s3; }
  __syncthreads();
  float S1=r1[0]+r1[1]+r1[2]+r1[3];
  float S2=r2[0]+r2[1]+r2[2]+r2[3];
  float S3=r3[0]+r3[1]+r3[2]+r3[3];
  float mu  = S1*(1.f/512.f);
  float var = S2*(1.f/512.f) - mu*mu;
  float rstd= rsqrtf(var + 1e-5f);
  float lr  = 0.01f/(1.f+__expf(-S3));
  tv[tid]     = ((v0-mu)*rstd - pr[tid])*lr;
  tv[tid+256] = ((v1-mu)*rstd - pr[tid+256])*lr;
}

// ---------------- 9. dout = erb @ wob^T (MFMA) -> doh + dot bf16 ----------------
__global__ __launch_bounds__(256) void k_gemm_dout(const short* __restrict__ erb,
    const short* __restrict__ wob, short* __restrict__ doh, short* __restrict__ dot){
  __shared__ __attribute__((aligned(16))) short as[64][LBK], bs[64][LBK];
  int r0=blockIdx.x<<6, h=blockIdx.y;
  f32x4 acc[4];
  #pragma unroll
  for(int nb=0;nb<4;nb++) acc[nb]=(f32x4){0.f,0.f,0.f,0.f};
  gemm64(erb+(size_t)r0*512, 512, wob+(size_t)h*32768, 512, 8, as, bs, acc);
  int tid=threadIdx.x, w=tid>>6, lane=tid&63, lg=lane>>4, ln=lane&15;
  size_t bh=(size_t)(r0>>11)*8+h;
  int n0=(r0&2047)+w*16+lg*4;
  #pragma unroll
  for(int nb=0;nb<4;nb++){
    int e=nb*16+ln;
    short4 s4;
    s4.x=f2bf(acc[nb][0]); s4.y=f2bf(acc[nb][1]);
    s4.z=f2bf(acc[nb][2]); s4.w=f2bf(acc[nb][3]);
    doh[(bh*2048+n0  )*64+e]=s4.x;
    doh[(bh*2048+n0+1)*64+e]=s4.y;
    doh[(bh*2048+n0+2)*64+e]=s4.z;
    doh[(bh*2048+n0+3)*64+e]=s4.w;
    *(short4*)&dot[(bh*64+e)*2048+n0]=s4;
  }
}

// ---------------- 10. delta = sum_e dout*out ----------------
__global__ __launch_bounds__(256) void k_delta(const short* __restrict__ doh,
    const short* __restrict__ obb, float* __restrict__ delta){
  int rid = blockIdx.x*4 + (threadIdx.x>>6);
  int lane = threadIdx.x&63;
  if(rid >= B_*H_*NM_) return;
  int b = rid/(H_*NM_); int rem = rid - b*H_*NM_;
  int h = rem/NM_; int i = rem - h*NM_;
  float v = bf2f(doh[((size_t)(b*H_+h)*N_ + i)*DH_ + lane])
          * bf2f(obb[((size_t)(b*N_+i))*D_ + h*DH_ + lane]);
  v = wred64(v);
  if(lane==0) delta[((size_t)(b*H_+h))*N_ + i] = v;
}

// ---------------- 11. flash backward dq (2-way j-split) -> dqt + dqp1 ----------------
__global__ __launch_bounds__(256) void k_fa_dq(const short* __restrict__ qh,
    const short* __restrict__ kh, const short* __restrict__ vh,
    const short* __restrict__ kt, const short* __restrict__ doh,
    const float* __restrict__ lse, const float* __restrict__ delta,
    short* __restrict__ dqt, short* __restrict__ dqp1){
  int bh = blockIdx.x, it = blockIdx.y, half = blockIdx.z;
  int i0 = it<<6;
  const short* qhb = qh + (size_t)bh*N_*DH_;
  const short* khb = kh + (size_t)bh*N_*DH_;
  const short* vhb = vh + (size_t)bh*N_*DH_;
  const short* ktb = kt + (size_t)bh*DH_*N_;
  const short* dohb= doh+ (size_t)bh*N_*DH_;
  __shared__ __attribute__((aligned(16))) short ks[64][LBK], vs[64][LBK], kts[64][LBK];
  __shared__ __attribute__((aligned(16))) short psb[4][16][LBK];
  int tid=threadIdx.x, w=tid>>6, lane=tid&63, lg=lane>>4, ln=lane&15;
  bf16x8 aq[2], ad[2];
  float Lr[4], dl[4];
  #pragma unroll
  for(int s=0;s<2;s++){
    aq[s]=*(const bf16x8*)&qhb[(size_t)(i0+w*16+ln)*DH_+32*s+lg*8];
    ad[s]=*(const bf16x8*)&dohb[(size_t)(i0+w*16+ln)*DH_+32*s+lg*8];
  }
  #pragma unroll
  for(int r=0;r<4;r++){
    int ii=i0+w*16+lg*4+r;
    Lr[r]=lse[(size_t)bh*N_+ii];
    dl[r]=(ii<NM_)?delta[(size_t)bh*N_+ii]:0.f;
  }
  f32x4 acc[4];
  #pragma unroll
  for(int nb=0;nb<4;nb++) acc[nb]=(f32x4){0.f,0.f,0.f,0.f};
  int4 ka0,ka1,va0,va1,ta0,ta1;
  tload(khb+(size_t)half*64*DH_, DH_, tid, ka0,ka1);
  tload(vhb+(size_t)half*64*DH_, DH_, tid, va0,va1);
  tload(ktb+half*64, N_, tid, ta0,ta1);
  for(int jt=half;jt<=it;jt+=2){
    int j0=jt<<6;
    bool msk_needed = (jt==it) || (it==31);
    __syncthreads();
    twrite(ks, tid, ka0,ka1);
    twrite(vs, tid, va0,va1);
    twrite(kts, tid, ta0,ta1);
    if(jt+2<=it){
      tload(khb+(size_t)(jt+2)*64*DH_, DH_, tid, ka0,ka1);
      tload(vhb+(size_t)(jt+2)*64*DH_, DH_, tid, va0,va1);
      tload(ktb+(jt+2)*64, N_, tid, ta0,ta1);
    }
    __syncthreads();
    f32x4 sv[4], dav[4];
    __builtin_amdgcn_s_setprio(1);
    #pragma unroll
    for(int nb=0;nb<4;nb++){
      f32x4 z={0.f,0.f,0.f,0.f}, zd={0.f,0.f,0.f,0.f};
      #pragma unroll
      for(int s=0;s<2;s++){
        bf16x8 bk=*(const bf16x8*)&ks[nb*16+ln][32*s+lg*8];
        bf16x8 bv=*(const bf16x8*)&vs[nb*16+ln][32*s+lg*8];
        z = MFMA_B16(aq[s], bk, z);
        zd= MFMA_B16(ad[s], bv, zd);
      }
      sv[nb]=z; dav[nb]=zd;
    }
    __builtin_amdgcn_s_setprio(0);
    if(msk_needed){
      #pragma unroll
      for(int r=0;r<4;r++){
        int ii=i0+w*16+lg*4+r;
        #pragma unroll
        for(int nb=0;nb<4;nb++){
          int jj=j0+nb*16+ln;
          float pv=__expf(sv[nb][r]*SCALE_F - Lr[r]);
          float dsv=SCALE_F*pv*(dav[nb][r]-dl[r]);
          if(jj>ii || ii>=NM_ || jj>=NM_) dsv=0.f;
          psb[w][lg*4+r][ln+16*nb]=f2bf(dsv);
        }
      }
    } else {
      #pragma unroll
      for(int r=0;r<4;r++)
        #pragma unroll
        for(int nb=0;nb<4;nb++){
          float pv=__expf(sv[nb][r]*SCALE_F - Lr[r]);
          psb[w][lg*4+r][ln+16*nb]=f2bf(SCALE_F*pv*(dav[nb][r]-dl[r]));
        }
    }
    lds_fence();
    __builtin_amdgcn_s_setprio(1);
    #pragma unroll
    for(int nb=0;nb<4;nb++){
      #pragma unroll
      for(int s=0;s<2;s++){
        bf16x8 pa = *(const bf16x8*)&psb[w][ln][32*s+lg*8];
        bf16x8 bk = *(const bf16x8*)&kts[nb*16+ln][32*s+lg*8];
        acc[nb]=MFMA_B16(pa,bk,acc[nb]);
      }
    }
    __builtin_amdgcn_s_setprio(0);
    lds_fence();
  }
  short* dst = half? dqp1 : dqt;
  #pragma unroll
  for(int nb=0;nb<4;nb++){
    short4 s4;
    s4.x=f2bf(acc[nb][0]); s4.y=f2bf(acc[nb][1]);
    s4.z=f2bf(acc[nb][2]); s4.w=f2bf(acc[nb][3]);
    *(short4*)&dst[((size_t)bh*64 + nb*16+ln)*2048 + i0+w*16+lg*4]=s4;
  }
}

// dqt += dqp1 (bf16, deterministic)
__global__ __launch_bounds__(256) void k_dqred(short* __restrict__ dqt,
    const short* __restrict__ dqp1){
  size_t i = ((size_t)blockIdx.x*256 + threadIdx.x)*8;
  int4 a = *(const int4*)&dqt[i];
  int4 b = *(const int4*)&dqp1[i];
  short* pa=(short*)&a; const short* pb=(const short*)&b;
  short out[8];
  #pragma unroll
  for(int k=0;k<8;k++) out[k]=f2bf(bf2f(pa[k])+bf2f(pb[k]));
  *(int4*)&dqt[i] = *(int4*)out;
}

// ---------------- 12. flash backward dk,dv (2-way i-split, single ps buffer) ----------------
// LDS cut 55.8->46.6 KB so 3 blocks/CU co-reside (was 2): ps holds P, then dS.
__global__ __launch_bounds__(256) void k_fa_dkv(const short* __restrict__ kh,
    const short* __restrict__ vh, const short* __restrict__ qh,
    const short* __restrict__ qt, const short* __restrict__ doh,
    const short* __restrict__ dot,
    const float* __restrict__ lse, const float* __restrict__ delta,
    short* __restrict__ dkt, short* __restrict__ dvt,
    short* __restrict__ dkp1, short* __restrict__ dvp1){
  int bh = blockIdx.x, jt = blockIdx.y, half = blockIdx.z;
  int j0 = jt<<6;
  const short* khb = kh + (size_t)bh*N_*DH_;
  const short* vhb = vh + (size_t)bh*N_*DH_;
  const short* qhb = qh + (size_t)bh*N_*DH_;
  const short* qtb = qt + (size_t)bh*DH_*N_;
  const short* dohb= doh+ (size_t)bh*N_*DH_;
  const short* dotb= dot+ (size_t)bh*DH_*N_;
  __shared__ __attribute__((aligned(16))) short qs[64][LBK], dos[64][LBK], qts[64][LBK], dots[64][LBK];
  __shared__ __attribute__((aligned(16))) short ps[4][16][LBK];
  __shared__ float Ls[64], dls[64];
  int tid=threadIdx.x, w=tid>>6, lane=tid&63, lg=lane>>4, ln=lane&15;
  bf16x8 akf[2], avf[2];
  #pragma unroll
  for(int s=0;s<2;s++){
    akf[s]=*(const bf16x8*)&khb[(size_t)(j0+w*16+ln)*DH_+32*s+lg*8];
    avf[s]=*(const bf16x8*)&vhb[(size_t)(j0+w*16+ln)*DH_+32*s+lg*8];
  }
  f32x4 accv[4], acck[4];
  #pragma unroll
  for(int nb=0;nb<4;nb++){
    accv[nb]=(f32x4){0.f,0.f,0.f,0.f};
    acck[nb]=(f32x4){0.f,0.f,0.f,0.f};
  }
  int it0 = jt + half;
  int4 qa0,qa1,da0,da1,qta0,qta1,dta0,dta1;
  float Lnx=0.f, dlnx=0.f;
  {
    int ip = (it0<32)? (it0<<6) : 0;
    tload(qhb+(size_t)ip*DH_, DH_, tid, qa0,qa1);
    tload(dohb+(size_t)ip*DH_, DH_, tid, da0,da1);
    tload(qtb+ip, N_, tid, qta0,qta1);
    tload(dotb+ip, N_, tid, dta0,dta1);
    if(tid<64){
      int ii=ip+tid;
      Lnx=lse[(size_t)bh*N_+ii];
      dlnx=(ii<NM_)?delta[(size_t)bh*N_+ii]:0.f;
    }
  }
  for(int it=it0; it<32; it+=2){
    int i0=it<<6;
    bool msk_needed = (it==jt) || (it==31);
    __syncthreads();
    twrite(qs, tid, qa0,qa1);
    twrite(dos, tid, da0,da1);
    twrite(qts, tid, qta0,qta1);
    twrite(dots, tid, dta0,dta1);
    if(tid<64){ Ls[tid]=Lnx; dls[tid]=dlnx; }
    if(it+2<32){
      int i1=(it+2)<<6;
      tload(qhb+(size_t)i1*DH_, DH_, tid, qa0,qa1);
      tload(dohb+(size_t)i1*DH_, DH_, tid, da0,da1);
      tload(qtb+i1, N_, tid, qta0,qta1);
      tload(dotb+i1, N_, tid, dta0,dta1);
      if(tid<64){
        int ii=i1+tid;
        Lnx=lse[(size_t)bh*N_+ii];
        dlnx=(ii<NM_)?delta[(size_t)bh*N_+ii]:0.f;
      }
    }
    __syncthreads();
    f32x4 sv[4], dav[4];
    __builtin_amdgcn_s_setprio(1);
    #pragma unroll
    for(int nb=0;nb<4;nb++){
      f32x4 z={0.f,0.f,0.f,0.f}, zd={0.f,0.f,0.f,0.f};
      #pragma unroll
      for(int s=0;s<2;s++){
        bf16x8 bq=*(const bf16x8*)&qs[nb*16+ln][32*s+lg*8];
        bf16x8 bd=*(const bf16x8*)&dos[nb*16+ln][32*s+lg*8];
        z = MFMA_B16(akf[s], bq, z);
        zd= MFMA_B16(avf[s], bd, zd);
      }
      sv[nb]=z; dav[nb]=zd;
    }
    __builtin_amdgcn_s_setprio(0);
    float dsk[4][4];
    if(msk_needed){
      #pragma unroll
      for(int nb=0;nb<4;nb++){
        float Lc=Ls[nb*16+ln], dlc=dls[nb*16+ln];
        int ii=i0+nb*16+ln;
        #pragma unroll
        for(int r=0;r<4;r++){
          int jj=j0+w*16+lg*4+r;
          float pv=__expf(sv[nb][r]*SCALE_F - Lc);
          bool msk=(jj>ii)||(ii>=NM_)||(jj>=NM_);
          if(msk) pv=0.f;
          ps[w][lg*4+r][ln+16*nb]=f2bf(pv);
          dsk[nb][r]= msk?0.f: SCALE_F*pv*(dav[nb][r]-dlc);
        }
      }
    } else {
      #pragma unroll
      for(int nb=0;nb<4;nb++){
        float Lc=Ls[nb*16+ln], dlc=dls[nb*16+ln];
        #pragma unroll
        for(int r=0;r<4;r++){
          float pv=__expf(sv[nb][r]*SCALE_F - Lc);
          ps[w][lg*4+r][ln+16*nb]=f2bf(pv);
          dsk[nb][r]= SCALE_F*pv*(dav[nb][r]-dlc);
        }
      }
    }
    lds_fence();
    __builtin_amdgcn_s_setprio(1);
    #pragma unroll
    for(int nb=0;nb<4;nb++){
      #pragma unroll
      for(int s=0;s<2;s++){
        bf16x8 pa = *(const bf16x8*)&ps[w][ln][32*s+lg*8];
        bf16x8 bd = *(const bf16x8*)&dots[nb*16+ln][32*s+lg*8];
        accv[nb]=MFMA_B16(pa,bd,accv[nb]);
      }
    }
    __builtin_amdgcn_s_setprio(0);
    lds_fence();
    #pragma unroll
    for(int nb=0;nb<4;nb++)
      #pragma unroll
      for(int r=0;r<4;r++)
        ps[w][lg*4+r][ln+16*nb]=f2bf(dsk[nb][r]);
    lds_fence();
    __builtin_amdgcn_s_setprio(1);
    #pragma unroll
    for(int nb=0;nb<4;nb++){
      #pragma unroll
      for(int s=0;s<2;s++){
        bf16x8 pk = *(const bf16x8*)&ps[w][ln][32*s+lg*8];
        bf16x8 bq = *(const bf16x8*)&qts[nb*16+ln][32*s+lg*8];
        acck[nb]=MFMA_B16(pk,bq,acck[nb]);
      }
    }
    __builtin_amdgcn_s_setprio(0);
    lds_fence();
  }
  short* dvd = half? dvp1 : dvt;
  short* dkd = half? dkp1 : dkt;
  #pragma unroll
  for(int nb=0;nb<4;nb++){
    int e=nb*16+ln, n0=j0+w*16+lg*4;
    short4 s4;
    s4.x=f2bf(accv[nb][0]); s4.y=f2bf(accv[nb][1]);
    s4.z=f2bf(accv[nb][2]); s4.w=f2bf(accv[nb][3]);
    *(short4*)&dvd[((size_t)bh*64+e)*2048 + n0]=s4;
    s4.x=f2bf(acck[nb][0]); s4.y=f2bf(acck[nb][1]);
    s4.z=f2bf(acck[nb][2]); s4.w=f2bf(acck[nb][3]);
    *(short4*)&dkd[((size_t)bh*64+e)*2048 + n0]=s4;
  }
}

// dkt += dkp1; dvt += dvp1
__global__ __launch_bounds__(256) void k_dkvred(short* __restrict__ dkt,
    short* __restrict__ dvt, const short* __restrict__ dkp1,
    const short* __restrict__ dvp1){
  int bid = blockIdx.x;
  short* dst; const short* src;
  if(bid<1024){ dst=dkt; src=dkp1; } else { dst=dvt; src=dvp1; bid-=1024; }
  size_t i = ((size_t)bid*256 + threadIdx.x)*8;
  int4 a = *(const int4*)&dst[i];
  int4 b = *(const int4*)&src[i];
  short* pa=(short*)&a; const short* pb=(const short*)&b;
  short out[8];
  #pragma unroll
  for(int k=0;k<8;k++) out[k]=f2bf(bf2f(pa[k])+bf2f(pb[k]));
  *(int4*)&dst[i] = *(int4*)out;
}

// ---------------- 13. weight grads (MFMA, split-K=8) ----------------
__global__ __launch_bounds__(256) void k_gemm_wgq(const short* __restrict__ tt,
    const short* __restrict__ g, float* __restrict__ par){
  __shared__ __attribute__((aligned(16))) short as[64][LBK], bs[64][LBK];
  int dt=blockIdx.x, h=blockIdx.y, sp=blockIdx.z;
  int b=sp>>2, n0b=(sp&3)*512;
  f32x4 acc[4];
  #pragma unroll
  for(int nb=0;nb<4;nb++) acc[nb]=(f32x4){0.f,0.f,0.f,0.f};
  gemm64(tt + (size_t)(dt*64)*4096 + sp*512, 4096,
         g  + ((size_t)(b*8+h)*64)*2048 + n0b, 2048, 8, as, bs, acc);
  int tid=threadIdx.x, w=tid>>6, lane=tid&63, lg=lane>>4, ln=lane&15;
  int row=w*16+lg*4;
  #pragma unroll
  for(int nb=0;nb<4;nb++)
    #pragma unroll
    for(int r=0;r<4;r++)
      par[(size_t)sp*262144 + (size_t)h*32768 + (size_t)(dt*64+row+r)*64 + nb*16+ln]=acc[nb][r];
}

__global__ __launch_bounds__(256) void k_gemm_wgo(const short* __restrict__ outt,
    const short* __restrict__ ert, float* __restrict__ par){
  __shared__ __attribute__((aligned(16))) short as[64][LBK], bs[64][LBK];
  int ct=blockIdx.x, h=blockIdx.y, sp=blockIdx.z;
  f32x4 acc[4];
  #pragma unroll
  for(int nb=0;nb<4;nb++) acc[nb]=(f32x4){0.f,0.f,0.f,0.f};
  gemm64(outt + (size_t)(h*64)*4096 + sp*512, 4096,
         ert  + (size_t)(ct*64)*4096 + sp*512, 4096, 8, as, bs, acc);
  int tid=threadIdx.x, w=tid>>6, lane=tid&63, lg=lane>>4, ln=lane&15;
  int row=w*16+lg*4;
  #pragma unroll
  for(int nb=0;nb<4;nb++)
    #pragma unroll
    for(int r=0;r<4;r++)
      par[(size_t)sp*262144 + (size_t)h*32768 + (size_t)(row+r)*512 + ct*64+nb*16+ln]=acc[nb][r];
}

__global__ __launch_bounds__(256) void k_wred_direct(const float* __restrict__ par,
    float* __restrict__ dst){
  int idx = blockIdx.x*256 + threadIdx.x;
  float s=0.f;
  #pragma unroll
  for(int sp=0;sp<8;sp++) s += par[(size_t)sp*262144 + idx];
  dst[idx]=s;
}
__global__ __launch_bounds__(256) void k_wred_xv(const float* __restrict__ par,
    float* __restrict__ X0){
  int idx = blockIdx.x*256 + threadIdx.x;
  float s=0.f;
  #pragma unroll
  for(int sp=0;sp<8;sp++) s += par[(size_t)sp*262144 + idx];
  int h=idx>>15, rem=idx&32767, d=rem>>6, e=rem&63;
  X0[(size_t)h*32768 + (size_t)e*512 + d]=s;
}
__global__ __launch_bounds__(256) void k_wred_xo(const float* __restrict__ par,
    float* __restrict__ X0){
  int idx = blockIdx.x*256 + threadIdx.x;
  float s=0.f;
  #pragma unroll
  for(int sp=0;sp<8;sp++) s += par[(size_t)sp*262144 + idx];
  X0[262144 + idx]=s;
}

// ---------------- 14. Newton-Schulz fused (16 blocks x 1024 threads) ----------------
__global__ __launch_bounds__(1024) void k_ns_fused(const float* __restrict__ X0,
    float* __restrict__ dwv, float* __restrict__ dwo){
  __shared__ __attribute__((aligned(16))) short Xl[64][520];
  __shared__ __attribute__((aligned(16))) short Xt[512][72];
  __shared__ __attribute__((aligned(16))) short Al[64][72];
  __shared__ __attribute__((aligned(16))) short Bl[64][72];
  __shared__ float red[16];
  int m = blockIdx.x, tid=threadIdx.x, w=tid>>6, lane=tid&63, lg=lane>>4, ln=lane&15;
  int wr=w>>2, wc=w&3;
  const float* Xg = X0 + (size_t)m*32768;
  float ss=0.f;
  for(int kk=0;kk<32;kk++){ float v=Xg[kk*1024+tid]; ss+=v*v; }
  ss=wred64(ss);
  if(lane==0) red[w]=ss;
  __syncthreads();
  float tot=0.f;
  #pragma unroll
  for(int i=0;i<16;i++) tot+=red[i];
  float sc = 1.f/fmaxf(sqrtf(tot), 1e-7f);
  for(int kk=0;kk<32;kk++){
    int idx=kk*1024+tid; int rr=idx>>9, cc=idx&511;
    short v=f2bf(Xg[idx]*sc);
    Xl[rr][cc]=v; Xt[cc][rr]=v;
  }
  __syncthreads();
  for(int iter=0; iter<5; ++iter){
    f32x4 accA=(f32x4){0.f,0.f,0.f,0.f};
    #pragma unroll
    for(int kt=0;kt<16;kt++){
      bf16x8 a = *(const bf16x8*)&Xl[wr*16+ln][kt*32+lg*8];
      bf16x8 b = *(const bf16x8*)&Xl[wc*16+ln][kt*32+lg*8];
      accA=MFMA_B16(a,b,accA);
    }
    #pragma unroll
    for(int r=0;r<4;r++) Al[wr*16+lg*4+r][wc*16+ln]=f2bf(accA[r]);
    __syncthreads();
    f32x4 acc2=(f32x4){0.f,0.f,0.f,0.f};
    #pragma unroll
    for(int s=0;s<2;s++){
      bf16x8 a = *(const bf16x8*)&Al[wr*16+ln][32*s+lg*8];
      bf16x8 b = *(const bf16x8*)&Al[wc*16+ln][32*s+lg*8];
      acc2=MFMA_B16(a,b,acc2);
    }
    #pragma unroll
    for(int r=0;r<4;r++)
      Bl[wr*16+lg*4+r][wc*16+ln]=f2bf(-4.775f*accA[r] + 2.0315f*acc2[r]);
    __syncthreads();
    int rg=(w&3)<<4, cg=(w>>2)<<7;
    f32x4 xn[8];
    #pragma unroll
    for(int nb=0;nb<8;nb++){
      xn[nb]=(f32x4){0.f,0.f,0.f,0.f};
      #pragma unroll
      for(int s=0;s<2;s++){
        bf16x8 a = *(const bf16x8*)&Bl[rg+ln][32*s+lg*8];
        bf16x8 b = *(const bf16x8*)&Xt[cg+nb*16+ln][32*s+lg*8];
        xn[nb]=MFMA_B16(a,b,xn[nb]);
      }
      #pragma unroll
      for(int r=0;r<4;r++)
        xn[nb][r] += 3.4445f*bf2f(Xl[rg+lg*4+r][cg+nb*16+ln]);
    }
    __syncthreads();
    if(iter<4){
      #pragma unroll
      for(int nb=0;nb<8;nb++){
        int d=cg+nb*16+ln, row0=rg+lg*4;
        short4 s4;
        s4.x=f2bf(xn[nb][0]); s4.y=f2bf(xn[nb][1]);
        s4.z=f2bf(xn[nb][2]); s4.w=f2bf(xn[nb][3]);
        Xl[row0  ][d]=s4.x; Xl[row0+1][d]=s4.y;
        Xl[row0+2][d]=s4.z; Xl[row0+3][d]=s4.w;
        *(short4*)&Xt[d][row0]=s4;
      }
      __syncthreads();
    } else {
      #pragma unroll
      for(int nb=0;nb<8;nb++){
        int d=cg+nb*16+ln, row0=rg+lg*4;
        #pragma unroll
        for(int r=0;r<4;r++){
          float v=xn[nb][r];
          int e=row0+r;
          if(m<8) dwv[(size_t)m*32768 + (size_t)d*64 + e]=v;
          else    dwo[(size_t)(m-8)*32768 + (size_t)e*512 + d]=v;
        }
      }
    }
  }
}

// ---------------- launch ----------------
extern "C" void kernel_launch(void* const* d_in, const int* in_sizes, int n_in,
                              void* d_out, int out_size, void* d_ws, size_t ws_size,
                              hipStream_t stream) {
  const float* tokens=(const float*)d_in[0];
  const float* rmsw =(const float*)d_in[1];
  const float* wq   =(const float*)d_in[2];
  const float* wk   =(const float*)d_in[3];
  const float* wv   =(const float*)d_in[4];
  const float* wo   =(const float*)d_in[5];
  const float* lrw  =(const float*)d_in[6];
  const float* tvw  =(const float*)d_in[7];
  float* out = (float*)d_out;
  float* ws  = (float*)d_ws;

  short* tb   = (short*)(ws);            // [4160][512] bf16 (pad rows zero)
  short* tt   = (short*)(ws + 1064960);  // [512][4096]
  short* qh   = (short*)(ws + 2113536);  // [16bh][2048][64]
  short* kh   = (short*)(ws + 3162112);
  short* vh   = (short*)(ws + 4210688);
  short* qt   = (short*)(ws + 5259264);  // [16bh][64][2048]
  short* kt   = (short*)(ws + 6307840);
  short* vt   = (short*)(ws + 7356416);
  float* er_  = ws + 8404992;            // f32 [4096][512]
  float* op0  = ws + 8404992;            // fwd partial 0 (dead before er_)
  short* dqp1 = (short*)(ws + 8404992);  // bwd partials (after er_ dead)
  short* dkp1 = (short*)(ws + 8404992);
  short* dvp1 = (short*)(ws + 9453568);
  short* obb  = (short*)(ws + 10502144); // bf16 [4096][512]
  short* outt = (short*)(ws + 11550720); // bf16 [512][4096]
  short* erb  = (short*)(ws + 12599296);
  short* ert  = (short*)(ws + 13647872);
  short* doh  = (short*)(ws + 14696448); // [16bh][2048][64]
  short* dot  = (short*)(ws + 15745024); // [16bh][64][2048]
  float* par_ = ws + 14696448;           // aliases doh+dot (dead before wgrad)
  float* op1  = ws + 14696448;           // fwd partial 1 (dead before doh/dot)
  short* dqt  = (short*)(ws + 16793600); // [16bh][64][2048]
  float* mlb  = ws + 16793600;           // fwd m/l partials (dead before dqt)
  short* dkt  = (short*)(ws + 17842176);
  short* dvt  = (short*)(ws + 18890752);
  short* wqt  = (short*)(ws + 19939328); // [8h][64][512]
  short* wkt  = (short*)(ws + 20070400);
  short* wvt  = (short*)(ws + 20201472);
  short* wob  = (short*)(ws + 20332544); // [512 he][512 d]
  short* wot  = (short*)(ws + 20463616); // [512 d][512 he]
  short* tvwb = (short*)(ws + 20594688); // [512 o][512 d]
  float* lse_ = ws + 20725760;
  float* dlt_ = ws + 20758528;
  float* X0_  = ws + 20791296;

  float* OUT_PRED = out;
  float* OUT_DWQ  = out + 2097152;
  float* OUT_DWK  = out + 2359296;
  float* OUT_DWV  = out + 2621440;
  float* OUT_DWO  = out + 2883584;

  k_rmsnorm<<<4160,256,0,stream>>>(tokens, rmsw, tb);
  k_wprep<<<272,256,0,stream>>>(wq,wk,wv,wo,tvw, wqt,wkt,wvt,wob,wot,tvwb);
  k_gemm_qkv<<<dim3(64,24),256,0,stream>>>(tb, wqt,wkt,wvt, qh,kh,vh, qt,kt,vt);
  k_fa_fwd<<<dim3(16,32,2),256,0,stream>>>(qh, kh, vt, op0, op1, mlb);
  k_fa_merge<<<8192,256,0,stream>>>(op0, op1, mlb, obb, lse_);
  k_gemm_pred<<<dim3(64,8),256,0,stream>>>(obb, wot, OUT_PRED);

  if(out_size < 3145728) return;   // forward-only variant

  k_trans_b<<<dim3(64,8),256,0,stream>>>(tb, tt);
  k_gemm_tv<<<dim3(64,8),256,0,stream>>>(tb, tvwb, er_);
  k_lnerr<<<4094,256,0,stream>>>(er_, tb, OUT_PRED, lrw);
  k_trans_f<<<dim3(64,8),256,0,stream>>>(er_, erb, ert);
  k_gemm_dout<<<dim3(64,8),256,0,stream>>>(erb, wob, doh, dot);
  k_delta<<<8188,256,0,stream>>>(doh, obb, dlt_);
  k_fa_dq<<<dim3(16,32,2),256,0,stream>>>(qh, kh, vh, kt, doh, lse_, dlt_, dqt, dqp1);
  k_dqred<<<1024,256,0,stream>>>(dqt, dqp1);
  k_fa_dkv<<<dim3(16,32,2),256,0,stream>>>(kh, vh, qh, qt, doh, dot, lse_, dlt_,
                                           dkt, dvt, dkp1, dvp1);
  k_dkvred<<<2048,256,0,stream>>>(dkt, dvt, dkp1, dvp1);
  k_trans_b<<<dim3(64,8),256,0,stream>>>(obb, outt);

  k_gemm_wgq<<<dim3(8,8,8),256,0,stream>>>(tt, dqt, par_);
  k_wred_direct<<<1024,256,0,stream>>>(par_, OUT_DWQ);
  k_gemm_wgq<<<dim3(8,8,8),256,0,stream>>>(tt, dkt, par_);
  k_wred_direct<<<1024,256,0,stream>>>(par_, OUT_DWK);
  k_gemm_wgq<<<dim3(8,8,8),256,0,stream>>>(tt, dvt, par_);
  k_wred_xv<<<1024,256,0,stream>>>(par_, X0_);
  k_gemm_wgo<<<dim3(8,8,8),256,0,stream>>>(outt, ert, par_);
  k_wred_xo<<<1024,256,0,stream>>>(par_, X0_);

  k_ns_fused<<<16,1024,0,stream>>>(X0_, OUT_DWV, OUT_DWO);
}

// Round 12
// 293.200 us; speedup vs baseline: 1.2037x; 1.0626x over previous
//
#include <hip/hip_runtime.h>
#include <float.h>
#include <math.h>

// ---------------- problem constants ----------------
#define B_   2
#define N_   2048
#define D_   512
#define H_   8
#define DH_  64
#define NM_  2047            // n-1
#define SCALE_F 0.125f       // 64^-0.5
#define LBK 72               // LDS row pad (bf16 tiles), 144B: 16B-aligned rows

typedef __attribute__((ext_vector_type(8))) short bf16x8;
typedef __attribute__((ext_vector_type(4))) float f32x4;
#define MFMA_B16(a,b,c) __builtin_amdgcn_mfma_f32_16x16x32_bf16(a,b,c,0,0,0)

__device__ __forceinline__ short f2bf(float f){
  unsigned u = __float_as_uint(f);
  unsigned r = u + 0x7fffu + ((u>>16)&1u);
  return (short)(r>>16);
}
__device__ __forceinline__ float bf2f(short s){
  return __uint_as_float(((unsigned)(unsigned short)s)<<16);
}
__device__ __forceinline__ void lds_fence(){
  asm volatile("s_waitcnt lgkmcnt(0)" ::: "memory");
  __builtin_amdgcn_sched_barrier(0);
}
__device__ __forceinline__ void tload(const short* __restrict__ src, size_t stride,
                                      int tid, int4& r0, int4& r1){
  int rr = tid>>2, cc = (tid&3)<<4;
  r0 = *(const int4*)&src[(size_t)rr*stride + cc];
  r1 = *(const int4*)&src[(size_t)rr*stride + cc + 8];
}
__device__ __forceinline__ void twrite(short (*dst)[LBK], int tid,
                                       const int4& r0, const int4& r1){
  int rr = tid>>2, cc = (tid&3)<<4;
  *(int4*)&dst[rr][cc]   = r0;
  *(int4*)&dst[rr][cc+8] = r1;
}
__device__ __forceinline__ float wred64(float v){
  #pragma unroll
  for(int off=32; off; off>>=1) v += __shfl_down(v, off, 64);
  return v;
}

// 64x64 MFMA GEMM mainloop with register-prefetch double buffering
__device__ __forceinline__ void gemm64(const short* __restrict__ A, size_t lda,
    const short* __restrict__ Bt, size_t ldb, int nk,
    short (*as)[LBK], short (*bs)[LBK], f32x4* acc){
  int tid=threadIdx.x, w=tid>>6, lane=tid&63, lg=lane>>4, ln=lane&15;
  int4 a0,a1,b0,b1;
  tload(A, lda, tid, a0,a1);
  tload(Bt, ldb, tid, b0,b1);
  for(int kt=0;kt<nk;++kt){
    __syncthreads();
    twrite(as, tid, a0,a1);
    twrite(bs, tid, b0,b1);
    if(kt+1<nk){
      tload(A +(size_t)(kt+1)*64, lda, tid, a0,a1);
      tload(Bt+(size_t)(kt+1)*64, ldb, tid, b0,b1);
    }
    __syncthreads();
    __builtin_amdgcn_s_setprio(1);
    #pragma unroll
    for(int s=0;s<2;s++){
      bf16x8 a = *(const bf16x8*)&as[w*16+ln][32*s+lg*8];
      #pragma unroll
      for(int nb=0;nb<4;nb++){
        bf16x8 b = *(const bf16x8*)&bs[nb*16+ln][32*s+lg*8];
        acc[nb]=MFMA_B16(a,b,acc[nb]);
      }
    }
    __builtin_amdgcn_s_setprio(0);
  }
}

// ---------------- 1. RMSNorm -> tb (bf16, padded to 4160 rows) ----------------
__global__ __launch_bounds__(256) void k_rmsnorm(const float* __restrict__ tok,
    const float* __restrict__ w, short* __restrict__ tb){
  int row = blockIdx.x;
  int tid = threadIdx.x;
  if(row>=4096){ tb[(size_t)row*D_+tid]=0; tb[(size_t)row*D_+tid+256]=0; return; }
  const float* x = tok + (size_t)row*D_;
  float v0 = x[tid], v1 = x[tid+256];
  float s = v0*v0 + v1*v1;
  s = wred64(s);
  __shared__ float red[4];
  if((tid&63)==0) red[tid>>6] = s;
  __syncthreads();
  float tot = red[0]+red[1]+red[2]+red[3];
  float sc = rsqrtf(tot*(1.f/512.f) + 1.1920929e-7f);
  tb[(size_t)row*D_+tid]     = f2bf(v0*sc*w[tid]);
  tb[(size_t)row*D_+tid+256] = f2bf(v1*sc*w[tid+256]);
}

// ---------------- 2. weight prep ----------------
__global__ __launch_bounds__(256) void k_wprep(const float* __restrict__ wq,
    const float* __restrict__ wk, const float* __restrict__ wv,
    const float* __restrict__ wo, const float* __restrict__ tvw,
    short* __restrict__ wqt, short* __restrict__ wkt, short* __restrict__ wvt,
    short* __restrict__ wob, short* __restrict__ wot, short* __restrict__ tvwb){
  __shared__ short l[64][66];
  int bx=blockIdx.x, tid=threadIdx.x;
  if(bx<192){
    const float* w = (bx<64)? wq : (bx<128)? wk : wv;
    short* wt      = (bx<64)? wqt: (bx<128)? wkt: wvt;
    int lb=bx&63, h=lb>>3, d0=(lb&7)*64;
    for(int kk=0;kk<16;kk++){
      int idx=kk*256+tid, rr=idx>>6, cc=idx&63;
      l[cc][rr] = f2bf(w[((size_t)h*512 + d0+rr)*64 + cc]);
    }
    __syncthreads();
    for(int kk=0;kk<16;kk++){
      int idx=kk*256+tid, rr=idx>>6, cc=idx&63;
      wt[((size_t)h*64+rr)*512 + d0+cc] = l[rr][cc];
    }
  } else if(bx<256){
    int lb=bx-192, r0=(lb>>3)*64, c0=(lb&7)*64;
    for(int kk=0;kk<16;kk++){
      int idx=kk*256+tid, rr=idx>>6, cc=idx&63;
      l[cc][rr] = f2bf(wo[(size_t)(r0+rr)*512 + c0+cc]);
    }
    __syncthreads();
    for(int kk=0;kk<16;kk++){
      int idx=kk*256+tid, rr=idx>>6, cc=idx&63;
      wot[(size_t)(c0+rr)*512 + r0+cc] = l[rr][cc];
    }
  } else if(bx<264){
    size_t base=(size_t)(bx-256)*32768;
    for(int kk=0;kk<128;kk++) wob[base+kk*256+tid]=f2bf(wo[base+kk*256+tid]);
  } else {
    size_t base=(size_t)(bx-264)*32768;
    for(int kk=0;kk<128;kk++) tvwb[base+kk*256+tid]=f2bf(tvw[base+kk*256+tid]);
  }
}

// ---------------- 3. transposes (4096x512) ----------------
__global__ __launch_bounds__(256) void k_trans_b(const short* __restrict__ in,
    short* __restrict__ outt){
  __shared__ short l[64][66];
  int r0=blockIdx.x<<6, c0=blockIdx.y<<6, tid=threadIdx.x;
  for(int kk=0;kk<16;kk++){
    int idx=kk*256+tid, rr=idx>>6, cc=idx&63;
    l[cc][rr]=in[(size_t)(r0+rr)*512 + c0+cc];
  }
  __syncthreads();
  for(int kk=0;kk<16;kk++){
    int idx=kk*256+tid, rr=idx>>6, cc=idx&63;
    outt[(size_t)(c0+rr)*4096 + r0+cc]=l[rr][cc];
  }
}
__global__ __launch_bounds__(256) void k_trans_f(const float* __restrict__ in,
    short* __restrict__ outn, short* __restrict__ outt){
  __shared__ short l[64][66];
  int r0=blockIdx.x<<6, c0=blockIdx.y<<6, tid=threadIdx.x;
  for(int kk=0;kk<16;kk++){
    int idx=kk*256+tid, rr=idx>>6, cc=idx&63;
    short v=f2bf(in[(size_t)(r0+rr)*512 + c0+cc]);
    outn[(size_t)(r0+rr)*512 + c0+cc]=v;
    l[cc][rr]=v;
  }
  __syncthreads();
  for(int kk=0;kk<16;kk++){
    int idx=kk*256+tid, rr=idx>>6, cc=idx&63;
    outt[(size_t)(c0+rr)*4096 + r0+cc]=l[rr][cc];
  }
}

// ---------------- 4. QKV projection (MFMA) ----------------
__global__ __launch_bounds__(256) void k_gemm_qkv(const short* __restrict__ tb,
    const short* __restrict__ wqt, const short* __restrict__ wkt, const short* __restrict__ wvt,
    short* __restrict__ qh, short* __restrict__ kh, short* __restrict__ vh,
    short* __restrict__ qt, short* __restrict__ kt, short* __restrict__ vt){
  __shared__ __attribute__((aligned(16))) short as[64][LBK], bs[64][LBK];
  int r0=blockIdx.x<<6, ct=blockIdx.y, which=ct>>3, h=ct&7;
  const short* Bt=(which==0?wqt:which==1?wkt:wvt)+(size_t)h*32768;
  f32x4 acc[4];
  #pragma unroll
  for(int nb=0;nb<4;nb++) acc[nb]=(f32x4){0.f,0.f,0.f,0.f};
  gemm64(tb+(size_t)r0*512, 512, Bt, 512, 8, as, bs, acc);
  short* on=(which==0?qh:which==1?kh:vh);
  short* ot=(which==0?qt:which==1?kt:vt);
  int tid=threadIdx.x, w=tid>>6, lane=tid&63, lg=lane>>4, ln=lane&15;
  size_t bh=(size_t)(r0>>11)*8+h;
  int n0=(r0&2047)+w*16+lg*4;
  #pragma unroll
  for(int nb=0;nb<4;nb++){
    int e=nb*16+ln;
    short4 s4;
    s4.x=f2bf(acc[nb][0]); s4.y=f2bf(acc[nb][1]);
    s4.z=f2bf(acc[nb][2]); s4.w=f2bf(acc[nb][3]);
    on[(bh*2048+n0  )*64+e]=s4.x;
    on[(bh*2048+n0+1)*64+e]=s4.y;
    on[(bh*2048+n0+2)*64+e]=s4.z;
    on[(bh*2048+n0+3)*64+e]=s4.w;
    *(short4*)&ot[(bh*64+e)*2048+n0]=s4;
  }
}

// ---------------- 5. flash attention forward (2-way j-split, partials) ----------------
__global__ __launch_bounds__(256) void k_fa_fwd(const short* __restrict__ qh,
    const short* __restrict__ kh, const short* __restrict__ vt,
    float* __restrict__ op0, float* __restrict__ op1, float* __restrict__ mlb){
  int bh = blockIdx.x, qq = blockIdx.y, half = blockIdx.z;
  int it = (qq<16)? (31-qq) : (qq-16);
  int i0 = it<<6;
  const short* qhb = qh + (size_t)bh*N_*DH_;
  const short* khb = kh + (size_t)bh*N_*DH_;
  const short* vtb = vt + (size_t)bh*DH_*N_;
  __shared__ __attribute__((aligned(16))) short ks[64][LBK], vts[64][LBK];
  __shared__ __attribute__((aligned(16))) short psb[4][16][LBK];
  int tid=threadIdx.x, w=tid>>6, lane=tid&63, lg=lane>>4, ln=lane&15;
  bf16x8 aq[2];
  #pragma unroll
  for(int s=0;s<2;s++)
    aq[s] = *(const bf16x8*)&qhb[(size_t)(i0+w*16+ln)*DH_ + 32*s + lg*8];
  f32x4 acc[4];
  float mrow[4], lrow[4];
  #pragma unroll
  for(int nb=0;nb<4;nb++) acc[nb]=(f32x4){0.f,0.f,0.f,0.f};
  #pragma unroll
  for(int r=0;r<4;r++){ mrow[r]=-FLT_MAX; lrow[r]=0.f; }
  int4 ka0,ka1,va0,va1;
  tload(khb+(size_t)half*64*DH_, DH_, tid, ka0,ka1);
  tload(vtb+half*64, N_, tid, va0,va1);
  for(int jt=half;jt<=it;jt+=2){
    int j0 = jt<<6;
    bool diag = (jt==it);
    __syncthreads();
    twrite(ks, tid, ka0,ka1);
    twrite(vts, tid, va0,va1);
    if(jt+2<=it){
      tload(khb+(size_t)(jt+2)*64*DH_, DH_, tid, ka0,ka1);
      tload(vtb+(jt+2)*64, N_, tid, va0,va1);
    }
    __syncthreads();
    f32x4 sv[4];
    __builtin_amdgcn_s_setprio(1);
    #pragma unroll
    for(int nb=0;nb<4;nb++){
      f32x4 z = {0.f,0.f,0.f,0.f};
      #pragma unroll
      for(int s=0;s<2;s++){
        bf16x8 bk = *(const bf16x8*)&ks[nb*16+ln][32*s + lg*8];
        z = MFMA_B16(aq[s], bk, z);
      }
      sv[nb]=z;
    }
    __builtin_amdgcn_s_setprio(0);
    int iiB = i0 + w*16 + lg*4;
    #pragma unroll
    for(int r=0;r<4;r++){
      int ii = iiB + r;
      float srow[4]; float mx = -FLT_MAX;
      if(diag){
        #pragma unroll
        for(int nb=0;nb<4;nb++){
          float x = sv[nb][r]*SCALE_F;
          if(j0+nb*16+ln > ii) x = -FLT_MAX;
          srow[nb]=x; mx=fmaxf(mx,x);
        }
      } else {
        #pragma unroll
        for(int nb=0;nb<4;nb++){
          float x = sv[nb][r]*SCALE_F;
          srow[nb]=x; mx=fmaxf(mx,x);
        }
      }
      mx=fmaxf(mx,__shfl_xor(mx,1)); mx=fmaxf(mx,__shfl_xor(mx,2));
      mx=fmaxf(mx,__shfl_xor(mx,4)); mx=fmaxf(mx,__shfl_xor(mx,8));
      float mn = fmaxf(mrow[r], mx);
      float rs = 0.f;
      #pragma unroll
      for(int nb=0;nb<4;nb++){
        float pv = __expf(srow[nb]-mn);
        psb[w][lg*4+r][ln+16*nb]=f2bf(pv); rs+=pv;
      }
      rs+=__shfl_xor(rs,1); rs+=__shfl_xor(rs,2);
      rs+=__shfl_xor(rs,4); rs+=__shfl_xor(rs,8);
      float corr = __expf(mrow[r]-mn);
      lrow[r]=lrow[r]*corr+rs; mrow[r]=mn;
      #pragma unroll
      for(int nb=0;nb<4;nb++) acc[nb][r]*=corr;
    }
    lds_fence();
    __builtin_amdgcn_s_setprio(1);
    #pragma unroll
    for(int nb=0;nb<4;nb++){
      #pragma unroll
      for(int s=0;s<2;s++){
        bf16x8 pa = *(const bf16x8*)&psb[w][ln][32*s + lg*8];
        bf16x8 bv = *(const bf16x8*)&vts[nb*16+ln][32*s + lg*8];
        acc[nb] = MFMA_B16(pa, bv, acc[nb]);
      }
    }
    __builtin_amdgcn_s_setprio(0);
    lds_fence();
  }
  float* op   = half? op1 : op0;
  float* marr = mlb + half*65536;
  float* larr = marr + 32768;
  #pragma unroll
  for(int r=0;r<4;r++){
    int ii = i0 + w*16 + lg*4 + r;
    size_t row = (size_t)bh*2048 + ii;
    #pragma unroll
    for(int nb=0;nb<4;nb++)
      op[row*64 + nb*16+ln] = acc[nb][r];
    if(ln==0){ marr[row]=mrow[r]; larr[row]=lrow[r]; }
  }
}

// merge two softmax partials -> obb bf16 + lse
__global__ __launch_bounds__(256) void k_fa_merge(const float* __restrict__ op0,
    const float* __restrict__ op1, const float* __restrict__ mlb,
    short* __restrict__ obb, float* __restrict__ lse){
  int row = blockIdx.x*4 + (threadIdx.x>>6);
  int lane = threadIdx.x&63;
  float m0 = mlb[row],        l0 = mlb[32768+row];
  float m1 = mlb[65536+row],  l1 = mlb[98304+row];
  float m  = fmaxf(m0,m1);
  float c0 = __expf(m0-m), c1 = __expf(m1-m);
  float l  = l0*c0 + l1*c1;
  float o  = (op0[(size_t)row*64+lane]*c0 + op1[(size_t)row*64+lane]*c1)/l;
  int bh = row>>11, i = row&2047, b = bh>>3, h = bh&7;
  obb[((size_t)(b*2048+i))*512 + h*64 + lane] = f2bf(o);
  if(lane==0) lse[row] = m + logf(l);
}

// ---------------- 6. pred = obb @ wot^T (MFMA), f32 out ----------------
__global__ __launch_bounds__(256) void k_gemm_pred(const short* __restrict__ obb,
    const short* __restrict__ wot, float* __restrict__ pred){
  __shared__ __attribute__((aligned(16))) short as[64][LBK], bs[64][LBK];
  int r0=blockIdx.x<<6, c0=blockIdx.y<<6;
  f32x4 acc[4];
  #pragma unroll
  for(int nb=0;nb<4;nb++) acc[nb]=(f32x4){0.f,0.f,0.f,0.f};
  gemm64(obb+(size_t)r0*512, 512, wot+(size_t)c0*512, 512, 8, as, bs, acc);
  int tid=threadIdx.x, w=tid>>6, lane=tid&63, lg=lane>>4, ln=lane&15;
  int row=r0+w*16+lg*4;
  #pragma unroll
  for(int nb=0;nb<4;nb++)
    #pragma unroll
    for(int r=0;r<4;r++)
      pred[(size_t)(row+r)*512 + c0+nb*16+ln]=acc[nb][r];
}

// ---------------- 7. tv = tb(shift+1) @ tvwb^T ----------------
__global__ __launch_bounds__(256) void k_gemm_tv(const short* __restrict__ tb,
    const short* __restrict__ tvwb, float* __restrict__ er){
  __shared__ __attribute__((aligned(16))) short as[64][LBK], bs[64][LBK];
  int r0=blockIdx.x<<6, c0=blockIdx.y<<6;
  f32x4 acc[4];
  #pragma unroll
  for(int nb=0;nb<4;nb++) acc[nb]=(f32x4){0.f,0.f,0.f,0.f};
  gemm64(tb+(size_t)(r0+1)*512, 512, tvwb+(size_t)c0*512, 512, 8, as, bs, acc);
  int tid=threadIdx.x, w=tid>>6, lane=tid&63, lg=lane>>4, ln=lane&15;
  int row=r0+w*16+lg*4;
  #pragma unroll
  for(int nb=0;nb<4;nb++)
    #pragma unroll
    for(int r=0;r<4;r++){
      float v=(((row+r)&2047)==2047)?0.f:acc[nb][r];
      er[(size_t)(row+r)*512 + c0+nb*16+ln]=v;
    }
}

// ---------------- 8. layernorm target + lr + error ----------------
__global__ __launch_bounds__(256) void k_lnerr(float* __restrict__ er,
    const short* __restrict__ tb, const float* __restrict__ pred,
    const float* __restrict__ lrw){
  int kr = blockIdx.x;
  int b = kr/NM_, n = kr-b*NM_;
  size_t row=(size_t)b*2048+n;
  float* tv = er + row*512;
  const short* tok = tb + row*512;
  const float* pr  = pred + row*512;
  int tid=threadIdx.x;
  float v0=tv[tid], v1=tv[tid+256];
  float s1=v0+v1, s2=v0*v0+v1*v1;
  float s3=bf2f(tok[tid])*lrw[tid] + bf2f(tok[tid+256])*lrw[tid+256];
  s1=wred64(s1); s2=wred64(s2); s3=wred64(s3);
  __shared__ float r1[4],r2[4],r3[4];
  if((tid&63)==0){ int w=tid>>6; r1[w]=s1; r2[w]=s2; r3[w]=s3; }
  __syncthreads();
  float S1=r1[0]+r1[1]+r1[2]+r1[3];
  float S2=r2[0]+r2[1]+r2[2]+r2[3];
  float S3=r3[0]+r3[1]+r3[2]+r3[3];
  float mu  = S1*(1.f/512.f);
  float var = S2*(1.f/512.f) - mu*mu;
  float rstd= rsqrtf(var + 1e-5f);
  float lr  = 0.01f/(1.f+__expf(-S3));
  tv[tid]     = ((v0-mu)*rstd - pr[tid])*lr;
  tv[tid+256] = ((v1-mu)*rstd - pr[tid+256])*lr;
}

// ---------------- 9. dout = erb @ wob^T (MFMA) -> doh + dot bf16 ----------------
__global__ __launch_bounds__(256) void k_gemm_dout(const short* __restrict__ erb,
    const short* __restrict__ wob, short* __restrict__ doh, short* __restrict__ dot){
  __shared__ __attribute__((aligned(16))) short as[64][LBK], bs[64][LBK];
  int r0=blockIdx.x<<6, h=blockIdx.y;
  f32x4 acc[4];
  #pragma unroll
  for(int nb=0;nb<4;nb++) acc[nb]=(f32x4){0.f,0.f,0.f,0.f};
  gemm64(erb+(size_t)r0*512, 512, wob+(size_t)h*32768, 512, 8, as, bs, acc);
  int tid=threadIdx.x, w=tid>>6, lane=tid&63, lg=lane>>4, ln=lane&15;
  size_t bh=(size_t)(r0>>11)*8+h;
  int n0=(r0&2047)+w*16+lg*4;
  #pragma unroll
  for(int nb=0;nb<4;nb++){
    int e=nb*16+ln;
    short4 s4;
    s4.x=f2bf(acc[nb][0]); s4.y=f2bf(acc[nb][1]);
    s4.z=f2bf(acc[nb][2]); s4.w=f2bf(acc[nb][3]);
    doh[(bh*2048+n0  )*64+e]=s4.x;
    doh[(bh*2048+n0+1)*64+e]=s4.y;
    doh[(bh*2048+n0+2)*64+e]=s4.z;
    doh[(bh*2048+n0+3)*64+e]=s4.w;
    *(short4*)&dot[(bh*64+e)*2048+n0]=s4;
  }
}

// ---------------- 10. delta = sum_e dout*out ----------------
__global__ __launch_bounds__(256) void k_delta(const short* __restrict__ doh,
    const short* __restrict__ obb, float* __restrict__ delta){
  int rid = blockIdx.x*4 + (threadIdx.x>>6);
  int lane = threadIdx.x&63;
  if(rid >= B_*H_*NM_) return;
  int b = rid/(H_*NM_); int rem = rid - b*H_*NM_;
  int h = rem/NM_; int i = rem - h*NM_;
  float v = bf2f(doh[((size_t)(b*H_+h)*N_ + i)*DH_ + lane])
          * bf2f(obb[((size_t)(b*N_+i))*D_ + h*DH_ + lane]);
  v = wred64(v);
  if(lane==0) delta[((size_t)(b*H_+h))*N_ + i] = v;
}

// ---------------- 11. fused flash backward: dq (z<2) + dkv (z>=2) ----------------
// grid (16 bh, 32 tile, 4): z in {0,1} -> dq half z; z in {2,3} -> dkv half z-2.
__global__ __launch_bounds__(256) void k_fa_bwd(const short* __restrict__ qh,
    const short* __restrict__ kh, const short* __restrict__ vh,
    const short* __restrict__ qt, const short* __restrict__ kt,
    const short* __restrict__ doh, const short* __restrict__ dot,
    const float* __restrict__ lse, const float* __restrict__ delta,
    short* __restrict__ dqt, short* __restrict__ dqp1,
    short* __restrict__ dkt, short* __restrict__ dvt,
    short* __restrict__ dkp1, short* __restrict__ dvp1){
  __shared__ __attribute__((aligned(16))) short t0[64][LBK], t1[64][LBK], t2[64][LBK], t3[64][LBK];
  __shared__ __attribute__((aligned(16))) short ps[4][16][LBK];
  __shared__ float Ls[64], dls[64];
  int bh = blockIdx.x, tid=threadIdx.x, w=tid>>6, lane=tid&63, lg=lane>>4, ln=lane&15;
  const short* qhb = qh + (size_t)bh*N_*DH_;
  const short* khb = kh + (size_t)bh*N_*DH_;
  const short* vhb = vh + (size_t)bh*N_*DH_;
  const short* qtb = qt + (size_t)bh*DH_*N_;
  const short* ktb = kt + (size_t)bh*DH_*N_;
  const short* dohb= doh+ (size_t)bh*N_*DH_;
  const short* dotb= dot+ (size_t)bh*DH_*N_;

  if(blockIdx.z < 2){
    // -------- dq path: t0=ks, t1=vs, t2=kts --------
    int it = blockIdx.y, half = blockIdx.z;
    int i0 = it<<6;
    bf16x8 aq[2], ad[2];
    float Lr[4], dl[4];
    #pragma unroll
    for(int s=0;s<2;s++){
      aq[s]=*(const bf16x8*)&qhb[(size_t)(i0+w*16+ln)*DH_+32*s+lg*8];
      ad[s]=*(const bf16x8*)&dohb[(size_t)(i0+w*16+ln)*DH_+32*s+lg*8];
    }
    #pragma unroll
    for(int r=0;r<4;r++){
      int ii=i0+w*16+lg*4+r;
      Lr[r]=lse[(size_t)bh*N_+ii];
      dl[r]=(ii<NM_)?delta[(size_t)bh*N_+ii]:0.f;
    }
    f32x4 acc[4];
    #pragma unroll
    for(int nb=0;nb<4;nb++) acc[nb]=(f32x4){0.f,0.f,0.f,0.f};
    int4 ka0,ka1,va0,va1,ta0,ta1;
    tload(khb+(size_t)half*64*DH_, DH_, tid, ka0,ka1);
    tload(vhb+(size_t)half*64*DH_, DH_, tid, va0,va1);
    tload(ktb+half*64, N_, tid, ta0,ta1);
    for(int jt=half;jt<=it;jt+=2){
      int j0=jt<<6;
      bool msk_needed = (jt==it) || (it==31);
      __syncthreads();
      twrite(t0, tid, ka0,ka1);
      twrite(t1, tid, va0,va1);
      twrite(t2, tid, ta0,ta1);
      if(jt+2<=it){
        tload(khb+(size_t)(jt+2)*64*DH_, DH_, tid, ka0,ka1);
        tload(vhb+(size_t)(jt+2)*64*DH_, DH_, tid, va0,va1);
        tload(ktb+(jt+2)*64, N_, tid, ta0,ta1);
      }
      __syncthreads();
      f32x4 sv[4], dav[4];
      __builtin_amdgcn_s_setprio(1);
      #pragma unroll
      for(int nb=0;nb<4;nb++){
        f32x4 z={0.f,0.f,0.f,0.f}, zd={0.f,0.f,0.f,0.f};
        #pragma unroll
        for(int s=0;s<2;s++){
          bf16x8 bk=*(const bf16x8*)&t0[nb*16+ln][32*s+lg*8];
          bf16x8 bv=*(const bf16x8*)&t1[nb*16+ln][32*s+lg*8];
          z = MFMA_B16(aq[s], bk, z);
          zd= MFMA_B16(ad[s], bv, zd);
        }
        sv[nb]=z; dav[nb]=zd;
      }
      __builtin_amdgcn_s_setprio(0);
      if(msk_needed){
        #pragma unroll
        for(int r=0;r<4;r++){
          int ii=i0+w*16+lg*4+r;
          #pragma unroll
          for(int nb=0;nb<4;nb++){
            int jj=j0+nb*16+ln;
            float pv=__expf(sv[nb][r]*SCALE_F - Lr[r]);
            float dsv=SCALE_F*pv*(dav[nb][r]-dl[r]);
            if(jj>ii || ii>=NM_ || jj>=NM_) dsv=0.f;
            ps[w][lg*4+r][ln+16*nb]=f2bf(dsv);
          }
        }
      } else {
        #pragma unroll
        for(int r=0;r<4;r++)
          #pragma unroll
          for(int nb=0;nb<4;nb++){
            float pv=__expf(sv[nb][r]*SCALE_F - Lr[r]);
            ps[w][lg*4+r][ln+16*nb]=f2bf(SCALE_F*pv*(dav[nb][r]-dl[r]));
          }
      }
      lds_fence();
      __builtin_amdgcn_s_setprio(1);
      #pragma unroll
      for(int nb=0;nb<4;nb++){
        #pragma unroll
        for(int s=0;s<2;s++){
          bf16x8 pa = *(const bf16x8*)&ps[w][ln][32*s+lg*8];
          bf16x8 bk = *(const bf16x8*)&t2[nb*16+ln][32*s+lg*8];
          acc[nb]=MFMA_B16(pa,bk,acc[nb]);
        }
      }
      __builtin_amdgcn_s_setprio(0);
      lds_fence();
    }
    short* dst = half? dqp1 : dqt;
    #pragma unroll
    for(int nb=0;nb<4;nb++){
      short4 s4;
      s4.x=f2bf(acc[nb][0]); s4.y=f2bf(acc[nb][1]);
      s4.z=f2bf(acc[nb][2]); s4.w=f2bf(acc[nb][3]);
      *(short4*)&dst[((size_t)bh*64 + nb*16+ln)*2048 + i0+w*16+lg*4]=s4;
    }
  } else {
    // -------- dkv path: t0=qs, t1=dos, t2=qts, t3=dots --------
    int jt = blockIdx.y, half = blockIdx.z-2;
    int j0 = jt<<6;
    bf16x8 akf[2], avf[2];
    #pragma unroll
    for(int s=0;s<2;s++){
      akf[s]=*(const bf16x8*)&khb[(size_t)(j0+w*16+ln)*DH_+32*s+lg*8];
      avf[s]=*(const bf16x8*)&vhb[(size_t)(j0+w*16+ln)*DH_+32*s+lg*8];
    }
    f32x4 accv[4], acck[4];
    #pragma unroll
    for(int nb=0;nb<4;nb++){
      accv[nb]=(f32x4){0.f,0.f,0.f,0.f};
      acck[nb]=(f32x4){0.f,0.f,0.f,0.f};
    }
    int it0 = jt + half;
    int4 qa0,qa1,da0,da1,qta0,qta1,dta0,dta1;
    float Lnx=0.f, dlnx=0.f;
    {
      int ip = (it0<32)? (it0<<6) : 0;
      tload(qhb+(size_t)ip*DH_, DH_, tid, qa0,qa1);
      tload(dohb+(size_t)ip*DH_, DH_, tid, da0,da1);
      tload(qtb+ip, N_, tid, qta0,qta1);
      tload(dotb+ip, N_, tid, dta0,dta1);
      if(tid<64){
        int ii=ip+tid;
        Lnx=lse[(size_t)bh*N_+ii];
        dlnx=(ii<NM_)?delta[(size_t)bh*N_+ii]:0.f;
      }
    }
    for(int it=it0; it<32; it+=2){
      int i0=it<<6;
      bool msk_needed = (it==jt) || (it==31);
      __syncthreads();
      twrite(t0, tid, qa0,qa1);
      twrite(t1, tid, da0,da1);
      twrite(t2, tid, qta0,qta1);
      twrite(t3, tid, dta0,dta1);
      if(tid<64){ Ls[tid]=Lnx; dls[tid]=dlnx; }
      if(it+2<32){
        int i1=(it+2)<<6;
        tload(qhb+(size_t)i1*DH_, DH_, tid, qa0,qa1);
        tload(dohb+(size_t)i1*DH_, DH_, tid, da0,da1);
        tload(qtb+i1, N_, tid, qta0,qta1);
        tload(dotb+i1, N_, tid, dta0,dta1);
        if(tid<64){
          int ii=i1+tid;
          Lnx=lse[(size_t)bh*N_+ii];
          dlnx=(ii<NM_)?delta[(size_t)bh*N_+ii]:0.f;
        }
      }
      __syncthreads();
      f32x4 sv[4], dav[4];
      __builtin_amdgcn_s_setprio(1);
      #pragma unroll
      for(int nb=0;nb<4;nb++){
        f32x4 z={0.f,0.f,0.f,0.f}, zd={0.f,0.f,0.f,0.f};
        #pragma unroll
        for(int s=0;s<2;s++){
          bf16x8 bq=*(const bf16x8*)&t0[nb*16+ln][32*s+lg*8];
          bf16x8 bd=*(const bf16x8*)&t1[nb*16+ln][32*s+lg*8];
          z = MFMA_B16(akf[s], bq, z);
          zd= MFMA_B16(avf[s], bd, zd);
        }
        sv[nb]=z; dav[nb]=zd;
      }
      __builtin_amdgcn_s_setprio(0);
      float dsk[4][4];
      if(msk_needed){
        #pragma unroll
        for(int nb=0;nb<4;nb++){
          float Lc=Ls[nb*16+ln], dlc=dls[nb*16+ln];
          int ii=i0+nb*16+ln;
          #pragma unroll
          for(int r=0;r<4;r++){
            int jj=j0+w*16+lg*4+r;
            float pv=__expf(sv[nb][r]*SCALE_F - Lc);
            bool msk=(jj>ii)||(ii>=NM_)||(jj>=NM_);
            if(msk) pv=0.f;
            ps[w][lg*4+r][ln+16*nb]=f2bf(pv);
            dsk[nb][r]= msk?0.f: SCALE_F*pv*(dav[nb][r]-dlc);
          }
        }
      } else {
        #pragma unroll
        for(int nb=0;nb<4;nb++){
          float Lc=Ls[nb*16+ln], dlc=dls[nb*16+ln];
          #pragma unroll
          for(int r=0;r<4;r++){
            float pv=__expf(sv[nb][r]*SCALE_F - Lc);
            ps[w][lg*4+r][ln+16*nb]=f2bf(pv);
            dsk[nb][r]= SCALE_F*pv*(dav[nb][r]-dlc);
          }
        }
      }
      lds_fence();
      __builtin_amdgcn_s_setprio(1);
      #pragma unroll
      for(int nb=0;nb<4;nb++){
        #pragma unroll
        for(int s=0;s<2;s++){
          bf16x8 pa = *(const bf16x8*)&ps[w][ln][32*s+lg*8];
          bf16x8 bd = *(const bf16x8*)&t3[nb*16+ln][32*s+lg*8];
          accv[nb]=MFMA_B16(pa,bd,accv[nb]);
        }
      }
      __builtin_amdgcn_s_setprio(0);
      lds_fence();
      #pragma unroll
      for(int nb=0;nb<4;nb++)
        #pragma unroll
        for(int r=0;r<4;r++)
          ps[w][lg*4+r][ln+16*nb]=f2bf(dsk[nb][r]);
      lds_fence();
      __builtin_amdgcn_s_setprio(1);
      #pragma unroll
      for(int nb=0;nb<4;nb++){
        #pragma unroll
        for(int s=0;s<2;s++){
          bf16x8 pk = *(const bf16x8*)&ps[w][ln][32*s+lg*8];
          bf16x8 bq = *(const bf16x8*)&t2[nb*16+ln][32*s+lg*8];
          acck[nb]=MFMA_B16(pk,bq,acck[nb]);
        }
      }
      __builtin_amdgcn_s_setprio(0);
      lds_fence();
    }
    short* dvd = half? dvp1 : dvt;
    short* dkd = half? dkp1 : dkt;
    #pragma unroll
    for(int nb=0;nb<4;nb++){
      int e=nb*16+ln, n0=j0+w*16+lg*4;
      short4 s4;
      s4.x=f2bf(accv[nb][0]); s4.y=f2bf(accv[nb][1]);
      s4.z=f2bf(accv[nb][2]); s4.w=f2bf(accv[nb][3]);
      *(short4*)&dvd[((size_t)bh*64+e)*2048 + n0]=s4;
      s4.x=f2bf(acck[nb][0]); s4.y=f2bf(acck[nb][1]);
      s4.z=f2bf(acck[nb][2]); s4.w=f2bf(acck[nb][3]);
      *(short4*)&dkd[((size_t)bh*64+e)*2048 + n0]=s4;
    }
  }
}

// fused partial reduce: dqt+=dqp1, dkt+=dkp1, dvt+=dvp1 (3072 blocks)
__global__ __launch_bounds__(256) void k_dred(short* __restrict__ dqt,
    short* __restrict__ dkt, short* __restrict__ dvt,
    const short* __restrict__ dqp1, const short* __restrict__ dkp1,
    const short* __restrict__ dvp1){
  int bid = blockIdx.x;
  short* dst; const short* src;
  if(bid<1024){ dst=dqt; src=dqp1; }
  else if(bid<2048){ dst=dkt; src=dkp1; bid-=1024; }
  else { dst=dvt; src=dvp1; bid-=2048; }
  size_t i = ((size_t)bid*256 + threadIdx.x)*8;
  int4 a = *(const int4*)&dst[i];
  int4 b = *(const int4*)&src[i];
  short* pa=(short*)&a; const short* pb=(const short*)&b;
  short out[8];
  #pragma unroll
  for(int k=0;k<8;k++) out[k]=f2bf(bf2f(pa[k])+bf2f(pb[k]));
  *(int4*)&dst[i] = *(int4*)out;
}

// ---------------- 13. fused weight grads (MFMA, split-K=8, all four) ----------------
// grid (8,8,32): z&7 = sp, z>>3 = which {0:dwq,1:dwk,2:dwv,3:dwo}
__global__ __launch_bounds__(256) void k_gemm_wg(const short* __restrict__ tt,
    const short* __restrict__ dqt, const short* __restrict__ dkt,
    const short* __restrict__ dvt, const short* __restrict__ outt,
    const short* __restrict__ ert,
    float* __restrict__ pA, float* __restrict__ pB,
    float* __restrict__ pC, float* __restrict__ pD){
  __shared__ __attribute__((aligned(16))) short as[64][LBK], bs[64][LBK];
  int x=blockIdx.x, h=blockIdx.y, z=blockIdx.z;
  int sp=z&7, which=z>>3;
  f32x4 acc[4];
  #pragma unroll
  for(int nb=0;nb<4;nb++) acc[nb]=(f32x4){0.f,0.f,0.f,0.f};
  int tid=threadIdx.x, w=tid>>6, lane=tid&63, lg=lane>>4, ln=lane&15;
  int row=w*16+lg*4;
  if(which<3){
    const short* g = which==0? dqt : which==1? dkt : dvt;
    float* par = which==0? pA : which==1? pB : pC;
    int b=sp>>2, n0b=(sp&3)*512;
    gemm64(tt + (size_t)(x*64)*4096 + sp*512, 4096,
           g  + ((size_t)(b*8+h)*64)*2048 + n0b, 2048, 8, as, bs, acc);
    #pragma unroll
    for(int nb=0;nb<4;nb++)
      #pragma unroll
      for(int r=0;r<4;r++)
        par[(size_t)sp*262144 + (size_t)h*32768 + (size_t)(x*64+row+r)*64 + nb*16+ln]=acc[nb][r];
  } else {
    gemm64(outt + (size_t)(h*64)*4096 + sp*512, 4096,
           ert  + (size_t)(x*64)*4096 + sp*512, 4096, 8, as, bs, acc);
    #pragma unroll
    for(int nb=0;nb<4;nb++)
      #pragma unroll
      for(int r=0;r<4;r++)
        pD[(size_t)sp*262144 + (size_t)h*32768 + (size_t)(row+r)*512 + x*64+nb*16+ln]=acc[nb][r];
  }
}

// fused split-K reduce: 4096 blocks, grp = bid>>10 selects output
__global__ __launch_bounds__(256) void k_wred(const float* __restrict__ pA,
    const float* __restrict__ pB, const float* __restrict__ pC,
    const float* __restrict__ pD, float* __restrict__ dwq,
    float* __restrict__ dwk, float* __restrict__ X0){
  int bid = blockIdx.x;
  int grp = bid>>10;
  int idx = (bid&1023)*256 + threadIdx.x;
  const float* par = grp==0? pA : grp==1? pB : grp==2? pC : pD;
  float s=0.f;
  #pragma unroll
  for(int sp=0;sp<8;sp++) s += par[(size_t)sp*262144 + idx];
  if(grp==0) dwq[idx]=s;
  else if(grp==1) dwk[idx]=s;
  else if(grp==2){
    int h=idx>>15, rem=idx&32767, d=rem>>6, e=rem&63;
    X0[(size_t)h*32768 + (size_t)e*512 + d]=s;
  } else X0[262144 + idx]=s;
}

// ---------------- 14. Newton-Schulz fused (16 blocks x 1024 threads) ----------------
__global__ __launch_bounds__(1024) void k_ns_fused(const float* __restrict__ X0,
    float* __restrict__ dwv, float* __restrict__ dwo){
  __shared__ __attribute__((aligned(16))) short Xl[64][520];
  __shared__ __attribute__((aligned(16))) short Xt[512][72];
  __shared__ __attribute__((aligned(16))) short Al[64][72];
  __shared__ __attribute__((aligned(16))) short Bl[64][72];
  __shared__ float red[16];
  int m = blockIdx.x, tid=threadIdx.x, w=tid>>6, lane=tid&63, lg=lane>>4, ln=lane&15;
  int wr=w>>2, wc=w&3;
  const float* Xg = X0 + (size_t)m*32768;
  float ss=0.f;
  for(int kk=0;kk<32;kk++){ float v=Xg[kk*1024+tid]; ss+=v*v; }
  ss=wred64(ss);
  if(lane==0) red[w]=ss;
  __syncthreads();
  float tot=0.f;
  #pragma unroll
  for(int i=0;i<16;i++) tot+=red[i];
  float sc = 1.f/fmaxf(sqrtf(tot), 1e-7f);
  for(int kk=0;kk<32;kk++){
    int idx=kk*1024+tid; int rr=idx>>9, cc=idx&511;
    short v=f2bf(Xg[idx]*sc);
    Xl[rr][cc]=v; Xt[cc][rr]=v;
  }
  __syncthreads();
  for(int iter=0; iter<5; ++iter){
    f32x4 accA=(f32x4){0.f,0.f,0.f,0.f};
    #pragma unroll
    for(int kt=0;kt<16;kt++){
      bf16x8 a = *(const bf16x8*)&Xl[wr*16+ln][kt*32+lg*8];
      bf16x8 b = *(const bf16x8*)&Xl[wc*16+ln][kt*32+lg*8];
      accA=MFMA_B16(a,b,accA);
    }
    #pragma unroll
    for(int r=0;r<4;r++) Al[wr*16+lg*4+r][wc*16+ln]=f2bf(accA[r]);
    __syncthreads();
    f32x4 acc2=(f32x4){0.f,0.f,0.f,0.f};
    #pragma unroll
    for(int s=0;s<2;s++){
      bf16x8 a = *(const bf16x8*)&Al[wr*16+ln][32*s+lg*8];
      bf16x8 b = *(const bf16x8*)&Al[wc*16+ln][32*s+lg*8];
      acc2=MFMA_B16(a,b,acc2);
    }
    #pragma unroll
    for(int r=0;r<4;r++)
      Bl[wr*16+lg*4+r][wc*16+ln]=f2bf(-4.775f*accA[r] + 2.0315f*acc2[r]);
    __syncthreads();
    int rg=(w&3)<<4, cg=(w>>2)<<7;
    f32x4 xn[8];
    #pragma unroll
    for(int nb=0;nb<8;nb++){
      xn[nb]=(f32x4){0.f,0.f,0.f,0.f};
      #pragma unroll
      for(int s=0;s<2;s++){
        bf16x8 a = *(const bf16x8*)&Bl[rg+ln][32*s+lg*8];
        bf16x8 b = *(const bf16x8*)&Xt[cg+nb*16+ln][32*s+lg*8];
        xn[nb]=MFMA_B16(a,b,xn[nb]);
      }
      #pragma unroll
      for(int r=0;r<4;r++)
        xn[nb][r] += 3.4445f*bf2f(Xl[rg+lg*4+r][cg+nb*16+ln]);
    }
    __syncthreads();
    if(iter<4){
      #pragma unroll
      for(int nb=0;nb<8;nb++){
        int d=cg+nb*16+ln, row0=rg+lg*4;
        short4 s4;
        s4.x=f2bf(xn[nb][0]); s4.y=f2bf(xn[nb][1]);
        s4.z=f2bf(xn[nb][2]); s4.w=f2bf(xn[nb][3]);
        Xl[row0  ][d]=s4.x; Xl[row0+1][d]=s4.y;
        Xl[row0+2][d]=s4.z; Xl[row0+3][d]=s4.w;
        *(short4*)&Xt[d][row0]=s4;
      }
      __syncthreads();
    } else {
      #pragma unroll
      for(int nb=0;nb<8;nb++){
        int d=cg+nb*16+ln, row0=rg+lg*4;
        #pragma unroll
        for(int r=0;r<4;r++){
          float v=xn[nb][r];
          int e=row0+r;
          if(m<8) dwv[(size_t)m*32768 + (size_t)d*64 + e]=v;
          else    dwo[(size_t)(m-8)*32768 + (size_t)e*512 + d]=v;
        }
      }
    }
  }
}

// ---------------- launch ----------------
extern "C" void kernel_launch(void* const* d_in, const int* in_sizes, int n_in,
                              void* d_out, int out_size, void* d_ws, size_t ws_size,
                              hipStream_t stream) {
  const float* tokens=(const float*)d_in[0];
  const float* rmsw =(const float*)d_in[1];
  const float* wq   =(const float*)d_in[2];
  const float* wk   =(const float*)d_in[3];
  const float* wv   =(const float*)d_in[4];
  const float* wo   =(const float*)d_in[5];
  const float* lrw  =(const float*)d_in[6];
  const float* tvw  =(const float*)d_in[7];
  float* out = (float*)d_out;
  float* ws  = (float*)d_ws;

  short* tb   = (short*)(ws);            // [4160][512] bf16 (pad rows zero)
  short* tt   = (short*)(ws + 1064960);  // [512][4096]
  short* qh   = (short*)(ws + 2113536);  // [16bh][2048][64]
  short* kh   = (short*)(ws + 3162112);
  short* vh   = (short*)(ws + 4210688);
  short* qt   = (short*)(ws + 5259264);  // [16bh][64][2048]
  short* kt   = (short*)(ws + 6307840);
  short* vt   = (short*)(ws + 7356416);
  float* er_  = ws + 8404992;            // f32 [4096][512]
  float* op0  = ws + 8404992;            // fwd partial 0 (dead before er_)
  short* dqp1 = (short*)(ws + 8404992);  // bwd partial (er_ dead by then)
  short* dvp1 = (short*)(ws + 9453568);
  short* obb  = (short*)(ws + 10502144); // bf16 [4096][512]
  short* dkp1 = (short*)(ws + 10502144); // aliases obb (dead after early trans_b)
  short* outt = (short*)(ws + 11550720); // bf16 [512][4096]
  short* erb  = (short*)(ws + 12599296);
  short* ert  = (short*)(ws + 13647872);
  short* doh  = (short*)(ws + 14696448); // [16bh][2048][64]
  short* dot  = (short*)(ws + 15745024); // [16bh][64][2048]
  float* op1  = ws + 14696448;           // fwd partial 1 (dead before doh/dot)
  float* parD = ws + 14696448;           // dwo partials (doh/dot dead after fa_bwd)
  short* dqt  = (short*)(ws + 16793600); // [16bh][64][2048]
  float* mlb  = ws + 16793600;           // fwd m/l partials (dead before dqt)
  short* dkt  = (short*)(ws + 17842176);
  short* dvt  = (short*)(ws + 18890752);
  float* parA = ws + 2113536;            // dwq partials (qh/kh dead after fa_bwd)
  float* parB = ws + 4210688;            // dwk partials (vh/qt dead)
  float* parC = ws + 6307840;            // dwv partials (kt/vt dead)
  short* wqt  = (short*)(ws + 19939328); // [8h][64][512]
  short* wkt  = (short*)(ws + 20070400);
  short* wvt  = (short*)(ws + 20201472);
  short* wob  = (short*)(ws + 20332544); // [512 he][512 d]
  short* wot  = (short*)(ws + 20463616); // [512 d][512 he]
  short* tvwb = (short*)(ws + 20594688); // [512 o][512 d]
  float* lse_ = ws + 20725760;
  float* dlt_ = ws + 20758528;
  float* X0_  = ws + 20791296;

  float* OUT_PRED = out;
  float* OUT_DWQ  = out + 2097152;
  float* OUT_DWK  = out + 2359296;
  float* OUT_DWV  = out + 2621440;
  float* OUT_DWO  = out + 2883584;

  k_rmsnorm<<<4160,256,0,stream>>>(tokens, rmsw, tb);
  k_wprep<<<272,256,0,stream>>>(wq,wk,wv,wo,tvw, wqt,wkt,wvt,wob,wot,tvwb);
  k_gemm_qkv<<<dim3(64,24),256,0,stream>>>(tb, wqt,wkt,wvt, qh,kh,vh, qt,kt,vt);
  k_fa_fwd<<<dim3(16,32,2),256,0,stream>>>(qh, kh, vt, op0, op1, mlb);
  k_fa_merge<<<8192,256,0,stream>>>(op0, op1, mlb, obb, lse_);
  k_gemm_pred<<<dim3(64,8),256,0,stream>>>(obb, wot, OUT_PRED);

  if(out_size < 3145728) return;   // forward-only variant

  k_trans_b<<<dim3(64,8),256,0,stream>>>(tb, tt);
  k_gemm_tv<<<dim3(64,8),256,0,stream>>>(tb, tvwb, er_);
  k_lnerr<<<4094,256,0,stream>>>(er_, tb, OUT_PRED, lrw);
  k_trans_f<<<dim3(64,8),256,0,stream>>>(er_, erb, ert);
  k_gemm_dout<<<dim3(64,8),256,0,stream>>>(erb, wob, doh, dot);
  k_delta<<<8188,256,0,stream>>>(doh, obb, dlt_);
  k_trans_b<<<dim3(64,8),256,0,stream>>>(obb, outt);   // obb dead after this
  k_fa_bwd<<<dim3(16,32,4),256,0,stream>>>(qh, kh, vh, qt, kt, doh, dot,
                                           lse_, dlt_, dqt, dqp1,
                                           dkt, dvt, dkp1, dvp1);
  k_dred<<<3072,256,0,stream>>>(dqt, dkt, dvt, dqp1, dkp1, dvp1);

  k_gemm_wg<<<dim3(8,8,32),256,0,stream>>>(tt, dqt, dkt, dvt, outt, ert,
                                           parA, parB, parC, parD);
  k_wred<<<4096,256,0,stream>>>(parA, parB, parC, parD, OUT_DWQ, OUT_DWK, X0_);

  k_ns_fused<<<16,1024,0,stream>>>(X0_, OUT_DWV, OUT_DWO);
}